// Round 1
// baseline (496.138 us; speedup 1.0000x reference)
//
#include <hip/hip_runtime.h>

namespace {

constexpr int B     = 2;
constexpr int C     = 16;
constexpr int PREVC = 16;
constexpr int NPTS  = 16384;
constexpr int M1    = 4096;
constexpr int M2    = 4096;
constexpr int D1    = 4;
constexpr int CORR  = 15;
constexpr int FILT  = 15;
constexpr int CIN   = 48;   // 2*C + PREV
constexpr int CO0   = 32;
constexpr int CO1   = 32;
constexpr int O0    = 64;
constexpr int O1    = 64;
constexpr float NEG = 0.1f;

constexpr int S1_ELEMS   = B * (M1 + 1) * 32;  // splat1: [slot][ch0..31], ch0-15 prev, ch16-31 feat1
constexpr int ONES_ELEMS = B * (M1 + 1);
constexpr int S2_ELEMS   = B * (M2 + 1) * 16;  // splat2: [slot][ch0..15]

__device__ __forceinline__ float leaky(float v) { return v > 0.f ? v : NEG * v; }

__global__ void k_zero(float* __restrict__ p, int n) {
  int i = blockIdx.x * 256 + threadIdx.x;
  int stride = gridDim.x * 256;
  for (; i < n; i += stride) p[i] = 0.f;
}

// one thread per (b,d,n): 16 channel atomics + 1 mass atomic
__global__ void k_splat(const float* __restrict__ prev, const float* __restrict__ bary,
                        const int* __restrict__ lo, float* __restrict__ splat1,
                        float* __restrict__ ones) {
  int t = blockIdx.x * 256 + threadIdx.x;
  if (t >= B * D1 * NPTS) return;
  int n = t % NPTS;
  int b = t / (D1 * NPTS);
  int slot = lo[t] + 1;               // batch-flattened slot in [0, B*(M1+1))
  float w = bary[t];
  atomicAdd(ones + slot, w);
  const float* pbase = prev + (size_t)b * PREVC * NPTS + n;
  float* s = splat1 + (size_t)slot * 32;
#pragma unroll
  for (int p = 0; p < PREVC; ++p)
    atomicAdd(s + p, w * pbase[(size_t)p * NPTS]);
}

// normalize prev channels by splatted mass; fill feat1 into ch16..31 (slot 0 = pad -> 0)
__global__ void k_norm1(const float* __restrict__ feat1, float* __restrict__ splat1,
                        const float* __restrict__ ones) {
  int t = blockIdx.x * 256 + threadIdx.x;
  if (t >= B * (M1 + 1) * 16) return;
  int c = t & 15;
  int slot = t >> 4;
  int m = slot % (M1 + 1);
  int b = slot / (M1 + 1);
  float scale = 1.0f / (ones[slot] + 1e-5f);
  splat1[(size_t)slot * 32 + c] *= scale;
  float fv = (m == 0) ? 0.f : feat1[((size_t)b * C + c) * M1 + (m - 1)];
  splat1[(size_t)slot * 32 + 16 + c] = fv;
}

__global__ void k_fill2(const float* __restrict__ feat2, float* __restrict__ splat2) {
  int t = blockIdx.x * 256 + threadIdx.x;
  if (t >= B * (M2 + 1) * 16) return;
  int c = t & 15;
  int slot = t >> 4;
  int m = slot % (M2 + 1);
  int b = slot / (M2 + 1);
  float fv = (m == 0) ? 0.f : feat2[((size_t)b * C + c) * M2 + (m - 1)];
  splat2[(size_t)slot * 16 + c] = fv;
}

// fused correlation conv + blur conv; one block (512 thr) per (b, n)
__global__ __launch_bounds__(512) void k_main(
    const float* __restrict__ splat1, const float* __restrict__ splat2,
    const int* __restrict__ pc1, const int* __restrict__ pc2,
    const float* __restrict__ cw0, const float* __restrict__ cb0,
    const float* __restrict__ cw1, const float* __restrict__ cb1,
    const float* __restrict__ bw0, const float* __restrict__ bb0,
    const float* __restrict__ bw1, const float* __restrict__ bb1,
    float* __restrict__ out) {
  __shared__ int   idx1[CORR];
  __shared__ int   idx2[FILT * CORR];
  __shared__ float s1[CORR][33];            // [k][i<32], padded stride 33
  __shared__ float s2[CORR * 16 * 16];      // [k][i<16][f16] -> lanes over f are conflict-free
  __shared__ float p1s[CO0][16];            // part1 partials per (o, f)
  __shared__ float xls[CO0][16];            // x[o][f]
  __shared__ float hls[CO1][16];            // h[o2][f]
  __shared__ float pd[O0 * 8];
  __shared__ float y0s[O0];

  int bid = blockIdx.x;
  int b = bid / M1;
  int n = bid % M1;
  int tid = threadIdx.x;

  if (tid < CORR)
    idx1[tid] = pc1[((size_t)b * CORR + tid) * M1 + n] + 1;
  if (tid < FILT * CORR)
    idx2[tid] = pc2[((size_t)b * FILT * CORR + tid) * M1 + n] + 1;
  __syncthreads();

  // gather splat1: 15 idx x 32 ch
  if (tid < CORR * 32) {
    int k = tid >> 5, i = tid & 31;
    s1[k][i] = splat1[((size_t)b * (M1 + 1) + idx1[k]) * 32 + i];
  }
  // gather splat2: 225 idx x 16 ch
  for (int e = tid; e < FILT * CORR * 16; e += 512) {
    int c = e & 15;
    int pair = e >> 4;                 // pair = f*CORR + k
    int f = pair / CORR, k = pair % CORR;
    float v = splat2[((size_t)b * (M2 + 1) + idx2[pair]) * 16 + c];
    s2[(k * 16 + c) * 16 + f] = v;
  }
  __syncthreads();

  int f = tid & 15;       // 0..15 (15 = inactive in per-f stages)
  int o = tid >> 4;       // 0..31

  // ---- stage B: f-dependent conv part + part1 partial (k = f slice) ----
  float acc = 0.f;
  if (f < CORR) {
    const float* w2 = cw0 + ((size_t)o * CIN + 32) * CORR;  // cw0[o][32+i][k]
#pragma unroll
    for (int k = 0; k < CORR; ++k) {
      const float* sv = &s2[(k * 16) * 16 + f];
#pragma unroll
      for (int i = 0; i < 16; ++i)
        acc += sv[i * 16] * w2[i * CORR + k];
    }
    float pp = 0.f;
    const float* w1 = cw0 + (size_t)o * CIN * CORR + f;     // cw0[o][i][f]
#pragma unroll
    for (int i = 0; i < 32; ++i)
      pp += s1[f][i] * w1[i * CORR];
    p1s[o][f] = pp;
  }
  __syncthreads();

  if (f < CORR) {
    float s = cb0[o] + acc;
#pragma unroll
    for (int ff = 0; ff < CORR; ++ff) s += p1s[o][ff];
    xls[o][f] = leaky(s);
  }
  __syncthreads();

  // ---- stage C: 1x1x1 conv ----
  if (f < CORR) {
    float h = cb1[o];
#pragma unroll
    for (int c2 = 0; c2 < CO0; ++c2) h += cw1[o * CO0 + c2] * xls[c2][f];
    hls[o][f] = leaky(h);
  }
  __syncthreads();

  // ---- stage D: blur conv over (c,f) ----
  {
    int o3 = tid >> 3, g = tid & 7;
    float p = 0.f;
    for (int ff = g; ff < CORR; ff += 8) {
      const float* w = bw0 + (size_t)o3 * CO1 * FILT + ff;  // bw0[o3][c][ff]
#pragma unroll
      for (int c2 = 0; c2 < CO1; ++c2) p += w[c2 * FILT] * hls[c2][ff];
    }
    pd[tid] = p;
  }
  __syncthreads();

  if (tid < O0) {
    float s = bb0[tid];
#pragma unroll
    for (int g = 0; g < 8; ++g) s += pd[tid * 8 + g];
    y0s[tid] = leaky(s);
  }
  __syncthreads();

  // ---- stage E: final 1x1 (no relu) ----
  if (tid < O1) {
    float s = bb1[tid];
#pragma unroll
    for (int c2 = 0; c2 < O0; ++c2) s += bw1[tid * O0 + c2] * y0s[c2];
    out[((size_t)b * O1 + tid) * M1 + n] = s;
  }
}

}  // namespace

extern "C" void kernel_launch(void* const* d_in, const int* in_sizes, int n_in,
                              void* d_out, int out_size, void* d_ws, size_t ws_size,
                              hipStream_t stream) {
  const float* feat1 = (const float*)d_in[0];
  const float* feat2 = (const float*)d_in[1];
  const float* prev  = (const float*)d_in[2];
  const float* bary  = (const float*)d_in[3];
  const float* cw0   = (const float*)d_in[4];
  const float* cb0   = (const float*)d_in[5];
  const float* cw1   = (const float*)d_in[6];
  const float* cb1   = (const float*)d_in[7];
  const float* bw0   = (const float*)d_in[8];
  const float* bb0   = (const float*)d_in[9];
  const float* bw1   = (const float*)d_in[10];
  const float* bb1   = (const float*)d_in[11];
  const int* lo   = (const int*)d_in[12];
  const int* pc1  = (const int*)d_in[13];
  const int* pc2  = (const int*)d_in[14];
  // d_in[15]/d_in[16]: max_hash_cnt1/2 (compile-time constants here)

  float* ws     = (float*)d_ws;
  float* splat1 = ws;
  float* ones   = ws + S1_ELEMS;
  float* splat2 = ws + S1_ELEMS + ONES_ELEMS;
  float* out    = (float*)d_out;

  hipLaunchKernelGGL(k_zero, dim3(512), dim3(256), 0, stream,
                     splat1, S1_ELEMS + ONES_ELEMS);
  hipLaunchKernelGGL(k_splat, dim3((B * D1 * NPTS + 255) / 256), dim3(256), 0, stream,
                     prev, bary, lo, splat1, ones);
  hipLaunchKernelGGL(k_norm1, dim3((B * (M1 + 1) * 16 + 255) / 256), dim3(256), 0, stream,
                     feat1, splat1, ones);
  hipLaunchKernelGGL(k_fill2, dim3((B * (M2 + 1) * 16 + 255) / 256), dim3(256), 0, stream,
                     feat2, splat2);
  hipLaunchKernelGGL(k_main, dim3(B * M1), dim3(512), 0, stream,
                     splat1, splat2, pc1, pc2, cw0, cb0, cw1, cb1,
                     bw0, bb0, bw1, bb1, out);
}

// Round 2
// 294.132 us; speedup vs baseline: 1.6868x; 1.6868x over previous
//
#include <hip/hip_runtime.h>

namespace {

constexpr int B     = 2;
constexpr int C     = 16;
constexpr int PREVC = 16;
constexpr int NPTS  = 16384;
constexpr int M1    = 4096;
constexpr int D1    = 4;
constexpr int CORR  = 15;
constexpr int FILT  = 15;
constexpr int CIN   = 48;   // 2*C + PREV
constexpr int CO0   = 32;
constexpr int O1    = 64;
constexpr int MS    = M1 + 1;   // 4097 slots per batch (M1 == M2)
constexpr float NEG = 0.1f;

// ---- workspace layout (float offsets, regions padded to 16-float mult) ----
constexpr size_t OFF_SP1  = 0;                               // splat1 [b][m][32]
constexpr size_t SZ_SP1   = (size_t)B * MS * 32;             // 262208
constexpr size_t OFF_ONES = OFF_SP1 + SZ_SP1;
constexpr size_t SZ_ONES  = ((size_t)B * MS + 15) & ~(size_t)15;  // 8208
constexpr size_t OFF_SP2  = OFF_ONES + SZ_ONES;              // splat2 [b][m][16]
constexpr size_t SZ_SP2   = (size_t)B * MS * 16;
constexpr size_t OFF_P    = OFF_SP2 + SZ_SP2;                // P [b][k][m][32]
constexpr size_t SZ_PQ    = (size_t)B * CORR * MS * 32;      // 3,933,120
constexpr size_t OFF_Q    = OFF_P + SZ_PQ;                   // Q [b][k][m][32]
constexpr size_t OFF_CWT  = OFF_Q + SZ_PQ;                   // cwT [k][i48][o32]
constexpr size_t SZ_CWT   = (size_t)CORR * CIN * 32;         // 23040
constexpr size_t OFF_W0R  = OFF_CWT + SZ_CWT;                // W0r [cf512][o64]
constexpr size_t SZ_W0R   = 512 * 64;
constexpr size_t OFF_H    = OFF_W0R + SZ_W0R;                // h [b][n][cf512]
constexpr size_t SZ_H     = (size_t)B * M1 * 512;            // 4,194,304
// total ~12.5M floats ~= 50 MB

__device__ __forceinline__ float leaky(float v) { return v > 0.f ? v : NEG * v; }

// ---------------- splat (atomics) ----------------
__global__ void k_splat(const float* __restrict__ prev, const float* __restrict__ bary,
                        const int* __restrict__ lo, float* __restrict__ splat1,
                        float* __restrict__ ones) {
  int t = blockIdx.x * 256 + threadIdx.x;
  if (t >= B * D1 * NPTS) return;
  int n = t % NPTS;
  int b = t / (D1 * NPTS);
  int slot = lo[t] + 1;                    // batch-flattened slot in [0, B*MS)
  float w = bary[t];
  atomicAdd(ones + slot, w);
  const float* pbase = prev + (size_t)b * PREVC * NPTS + n;
  float* s = splat1 + (size_t)slot * 32;
#pragma unroll
  for (int p = 0; p < PREVC; ++p)
    atomicAdd(s + p, w * pbase[(size_t)p * NPTS]);
}

// ---------------- normalize + fill feat1/feat2 ----------------
__global__ void k_fill(const float* __restrict__ feat1, const float* __restrict__ feat2,
                       float* __restrict__ splat1, float* __restrict__ splat2,
                       const float* __restrict__ ones) {
  int t = blockIdx.x * 256 + threadIdx.x;
  if (t >= B * MS * 16) return;
  int c = t & 15;
  int slot = t >> 4;
  int m = slot % MS;
  int b = slot / MS;
  float scale = 1.0f / (ones[slot] + 1e-5f);
  splat1[(size_t)slot * 32 + c] *= scale;
  float f1 = (m == 0) ? 0.f : feat1[((size_t)b * C + c) * M1 + (m - 1)];
  splat1[(size_t)slot * 32 + 16 + c] = f1;
  float f2 = (m == 0) ? 0.f : feat2[((size_t)b * C + c) * M1 + (m - 1)];
  splat2[(size_t)slot * 16 + c] = f2;
}

// ---------------- weight prep: cwT[k][i][o], W0r[cf][o3] ----------------
__global__ void k_wprep(const float* __restrict__ cw0, const float* __restrict__ bw0,
                        float* __restrict__ cwT, float* __restrict__ W0r) {
  int e = blockIdx.x * 256 + threadIdx.x;
  if (e < CORR * CIN * 32) {
    int o = e & 31, i = (e >> 5) % CIN, k = e / (CIN * 32);
    cwT[e] = cw0[((size_t)o * CIN + i) * CORR + k];
  }
  int e2 = e - CORR * CIN * 32;
  if (e2 >= 0 && e2 < 512 * 64) {
    int o3 = e2 & 63, cf = e2 >> 6, c = cf >> 4, f = cf & 15;
    W0r[e2] = (f < FILT) ? bw0[((size_t)o3 * CO0 + c) * FILT + f] : 0.f;
  }
}

// ---------------- per-slot projections P, Q ----------------
// P[b][k][m][o] = sum_{i<16} splat2[b][m][i] * cw0[o][32+i][k]
// Q[b][k][m][o] = sum_{i<32} splat1[b][m][i] * cw0[o][i][k]
__global__ __launch_bounds__(256) void k_pq(const float* __restrict__ sp1,
                                            const float* __restrict__ sp2,
                                            const float* __restrict__ cwT,
                                            float* __restrict__ Pt, float* __restrict__ Qt) {
  __shared__ float wk[CIN][33];
  int k = blockIdx.y, b = blockIdx.z;
  int m0 = blockIdx.x * 16;
  int tid = threadIdx.x;
  for (int e = tid; e < CIN * 32; e += 256) {
    int i = e >> 5, o = e & 31;
    wk[i][o] = cwT[((size_t)k * CIN + i) * 32 + o];
  }
  __syncthreads();
  int o = tid & 31;
  int ml = tid >> 5;
  size_t outbase = ((size_t)(b * CORR + k) * MS) * 32;
#pragma unroll
  for (int r = 0; r < 2; ++r) {
    int m = m0 + ml + r * 8;
    if (m < MS) {
      const float* s1 = sp1 + ((size_t)b * MS + m) * 32;
      const float* s2 = sp2 + ((size_t)b * MS + m) * 16;
      float q = 0.f, p = 0.f;
#pragma unroll
      for (int i4 = 0; i4 < 8; ++i4) {
        float4 s = *(const float4*)(s1 + i4 * 4);
        q += s.x * wk[i4 * 4 + 0][o] + s.y * wk[i4 * 4 + 1][o] +
             s.z * wk[i4 * 4 + 2][o] + s.w * wk[i4 * 4 + 3][o];
      }
#pragma unroll
      for (int i4 = 0; i4 < 4; ++i4) {
        float4 s = *(const float4*)(s2 + i4 * 4);
        p += s.x * wk[32 + i4 * 4 + 0][o] + s.y * wk[32 + i4 * 4 + 1][o] +
             s.z * wk[32 + i4 * 4 + 2][o] + s.w * wk[32 + i4 * 4 + 3][o];
      }
      Qt[outbase + (size_t)m * 32 + o] = q;
      Pt[outbase + (size_t)m * 32 + o] = p;
    }
  }
}

// ---------------- gather + corr-conv (both layers) ----------------
// one block per (b,n); 512 thr = (o = tid&31) x (f = tid>>5)
__global__ __launch_bounds__(512) void k_gather(const float* __restrict__ Pt,
                                                const float* __restrict__ Qt,
                                                const int* __restrict__ pc1,
                                                const int* __restrict__ pc2,
                                                const float* __restrict__ cw1,
                                                const float* __restrict__ cb0,
                                                const float* __restrict__ cb1,
                                                float* __restrict__ hbuf) {
  __shared__ int   idx1[CORR];
  __shared__ int   idx2[FILT * CORR];
  __shared__ float p1s[32];
  __shared__ float xls[CORR][36];
  __shared__ float hT[32 * 17];

  int bid = blockIdx.x;
  int b = bid >> 12;
  int n = bid & (M1 - 1);
  int tid = threadIdx.x;
  int o = tid & 31, f = tid >> 5;

  if (tid < CORR)        idx1[tid] = pc1[((size_t)b * CORR + tid) * M1 + n] + 1;
  if (tid < FILT * CORR) idx2[tid] = pc2[((size_t)b * FILT * CORR + tid) * M1 + n] + 1;

  // preload conv2 (1x1) weights for this thread's o
  float wreg[32];
#pragma unroll
  for (int c4 = 0; c4 < 8; ++c4) {
    float4 w = *(const float4*)(cw1 + o * CO0 + c4 * 4);
    wreg[c4 * 4 + 0] = w.x; wreg[c4 * 4 + 1] = w.y;
    wreg[c4 * 4 + 2] = w.z; wreg[c4 * 4 + 3] = w.w;
  }
  __syncthreads();

  float acc = 0.f;
  if (f < CORR) {
    const float* Pb = Pt + (size_t)b * CORR * MS * 32;
#pragma unroll
    for (int k = 0; k < CORR; ++k)
      acc += Pb[((size_t)k * MS + idx2[f * CORR + k]) * 32 + o];
  } else {
    const float* Qb = Qt + (size_t)b * CORR * MS * 32;
    float p = 0.f;
#pragma unroll
    for (int k = 0; k < CORR; ++k)
      p += Qb[((size_t)k * MS + idx1[k]) * 32 + o];
    p1s[o] = p;
  }
  __syncthreads();

  if (f < CORR) {
    float x = acc + p1s[o] + cb0[o];
    xls[f][o] = leaky(x);
  }
  __syncthreads();

  if (f < CORR) {
    float h = cb1[o];
#pragma unroll
    for (int c4 = 0; c4 < 8; ++c4) {
      float4 xv = *(const float4*)(&xls[f][c4 * 4]);
      h += wreg[c4 * 4 + 0] * xv.x + wreg[c4 * 4 + 1] * xv.y +
           wreg[c4 * 4 + 2] * xv.z + wreg[c4 * 4 + 3] * xv.w;
    }
    hT[o * 17 + f] = leaky(h);
  } else {
    hT[o * 17 + 15] = 0.f;   // cf with f==15: padded zero row
  }
  __syncthreads();

  // coalesced store: h[b][n][cf], cf = o*16+f
  {
    int oo = tid >> 4, ff = tid & 15;
    hbuf[((size_t)b * M1 + n) * 512 + tid] = hT[oo * 17 + ff];
  }
}

// ---------------- blur conv: y0 = leaky(W0 h + b0); out = W1 y0 + b1 ----------------
// grid: (b, n-tile of 32) -> 256 blocks; 256 threads
__global__ __launch_bounds__(256) void k_blur(const float* __restrict__ hbuf,
                                              const float* __restrict__ W0r,
                                              const float* __restrict__ bb0,
                                              const float* __restrict__ bw1,
                                              const float* __restrict__ bb1,
                                              float* __restrict__ out) {
  __shared__ float hs[64][33];
  __shared__ float ws[64][68];
  __shared__ float y0s[64][36];

  int bid = blockIdx.x;
  int b = bid >> 7;
  int n0 = (bid & 127) * 32;
  int tid = threadIdx.x;
  int og = tid & 15, ng = tid >> 4;

  float acc[4][2] = {};
  for (int kc = 0; kc < 512; kc += 64) {
    __syncthreads();
    // stage h chunk, transposed in LDS: hs[kk][nn] = h[b][n0+nn][kc+kk]
    for (int e = tid; e < 512; e += 256) {
      int nn = e >> 4, k4 = e & 15;
      float4 v = *(const float4*)(hbuf + ((size_t)b * M1 + n0 + nn) * 512 + kc + k4 * 4);
      hs[k4 * 4 + 0][nn] = v.x; hs[k4 * 4 + 1][nn] = v.y;
      hs[k4 * 4 + 2][nn] = v.z; hs[k4 * 4 + 3][nn] = v.w;
    }
    // stage W0 chunk: ws[kk][o3]
    for (int e = tid; e < 1024; e += 256) {
      int row = e >> 4, c4 = e & 15;
      *(float4*)&ws[row][c4 * 4] = *(const float4*)(W0r + (size_t)(kc + row) * 64 + c4 * 4);
    }
    __syncthreads();
#pragma unroll 16
    for (int kk = 0; kk < 64; ++kk) {
      float4 w = *(const float4*)&ws[kk][og * 4];
      float h0 = hs[kk][ng * 2], h1 = hs[kk][ng * 2 + 1];
      acc[0][0] += w.x * h0; acc[0][1] += w.x * h1;
      acc[1][0] += w.y * h0; acc[1][1] += w.y * h1;
      acc[2][0] += w.z * h0; acc[2][1] += w.z * h1;
      acc[3][0] += w.w * h0; acc[3][1] += w.w * h1;
    }
  }
  __syncthreads();   // done reading ws/hs

#pragma unroll
  for (int i = 0; i < 4; ++i) {
    int o3 = og * 4 + i;
    float bias = bb0[o3];
#pragma unroll
    for (int j = 0; j < 2; ++j)
      y0s[o3][ng * 2 + j] = leaky(acc[i][j] + bias);
  }
  // restage bw1 transposed into ws: ws[c][o1]
  for (int e = tid; e < 64 * 64; e += 256) {
    int o1e = e >> 6, c = e & 63;
    ws[c][o1e] = bw1[e];
  }
  __syncthreads();

  int o1 = tid & 63, ng4 = tid >> 6;
  float a8[8] = {};
  for (int c = 0; c < 64; ++c) {
    float w = ws[c][o1];
    float4 ya = *(const float4*)&y0s[c][ng4 * 8];
    float4 yb = *(const float4*)&y0s[c][ng4 * 8 + 4];
    a8[0] += w * ya.x; a8[1] += w * ya.y; a8[2] += w * ya.z; a8[3] += w * ya.w;
    a8[4] += w * yb.x; a8[5] += w * yb.y; a8[6] += w * yb.z; a8[7] += w * yb.w;
  }
  float bias = bb1[o1];
#pragma unroll
  for (int j = 0; j < 8; ++j)
    out[((size_t)b * O1 + o1) * M1 + n0 + ng4 * 8 + j] = a8[j] + bias;
}

}  // namespace

extern "C" void kernel_launch(void* const* d_in, const int* in_sizes, int n_in,
                              void* d_out, int out_size, void* d_ws, size_t ws_size,
                              hipStream_t stream) {
  const float* feat1 = (const float*)d_in[0];
  const float* feat2 = (const float*)d_in[1];
  const float* prev  = (const float*)d_in[2];
  const float* bary  = (const float*)d_in[3];
  const float* cw0   = (const float*)d_in[4];
  const float* cb0   = (const float*)d_in[5];
  const float* cw1   = (const float*)d_in[6];
  const float* cb1   = (const float*)d_in[7];
  const float* bw0   = (const float*)d_in[8];
  const float* bb0   = (const float*)d_in[9];
  const float* bw1   = (const float*)d_in[10];
  const float* bb1   = (const float*)d_in[11];
  const int* lo  = (const int*)d_in[12];
  const int* pc1 = (const int*)d_in[13];
  const int* pc2 = (const int*)d_in[14];

  float* ws     = (float*)d_ws;
  float* splat1 = ws + OFF_SP1;
  float* ones   = ws + OFF_ONES;
  float* splat2 = ws + OFF_SP2;
  float* Pt     = ws + OFF_P;
  float* Qt     = ws + OFF_Q;
  float* cwT    = ws + OFF_CWT;
  float* W0r    = ws + OFF_W0R;
  float* hbuf   = ws + OFF_H;
  float* out    = (float*)d_out;

  hipMemsetAsync(splat1, 0, (SZ_SP1 + SZ_ONES) * sizeof(float), stream);

  hipLaunchKernelGGL(k_wprep, dim3((CORR * CIN * 32 + 512 * 64 + 255) / 256), dim3(256),
                     0, stream, cw0, bw0, cwT, W0r);
  hipLaunchKernelGGL(k_splat, dim3((B * D1 * NPTS + 255) / 256), dim3(256), 0, stream,
                     prev, bary, lo, splat1, ones);
  hipLaunchKernelGGL(k_fill, dim3((B * MS * 16 + 255) / 256), dim3(256), 0, stream,
                     feat1, feat2, splat1, splat2, ones);
  hipLaunchKernelGGL(k_pq, dim3((MS + 15) / 16, CORR, B), dim3(256), 0, stream,
                     splat1, splat2, cwT, Pt, Qt);
  hipLaunchKernelGGL(k_gather, dim3(B * M1), dim3(512), 0, stream,
                     Pt, Qt, pc1, pc2, cw1, cb0, cb1, hbuf);
  hipLaunchKernelGGL(k_blur, dim3(B * M1 / 32), dim3(256), 0, stream,
                     hbuf, W0r, bb0, bw1, bb1, out);
}

// Round 3
// 202.761 us; speedup vs baseline: 2.4469x; 1.4506x over previous
//
#include <hip/hip_runtime.h>
#include <hip/hip_bf16.h>

namespace {

constexpr int B     = 2;
constexpr int C     = 16;
constexpr int PREVC = 16;
constexpr int NPTS  = 16384;
constexpr int M1    = 4096;
constexpr int D1    = 4;
constexpr int CORR  = 15;
constexpr int FILT  = 15;
constexpr int CIN   = 48;
constexpr int CO0   = 32;
constexpr int O1    = 64;
constexpr int MS    = M1 + 1;        // 4097
constexpr int NSLOT = B * MS;        // 8194
constexpr int NPAIR = B * D1 * NPTS; // 131072
constexpr int NSCAN = 8256;          // 129 * 64 >= NSLOT+1
constexpr int GSTR  = 240;           // per-point index record: 225 idx2 + 15 idx1
constexpr float NEG = 0.1f;

// ---- workspace layout (float units) ----
constexpr size_t OFF_SP1   = 0;                            // splat1 [slot][32]
constexpr size_t SZ_SP1    = (size_t)NSLOT * 32;           // 262,208
constexpr size_t OFF_SP2   = OFF_SP1 + SZ_SP1;             // splat2 [slot][16]
constexpr size_t SZ_SP2    = (size_t)NSLOT * 16;
constexpr size_t OFF_P     = OFF_SP2 + SZ_SP2;             // P bf16 [b][k][m][32]
constexpr size_t SZ_PQ     = (size_t)B * CORR * MS * 32 / 2;  // in floats (bf16 x2)
constexpr size_t OFF_Q     = OFF_P + SZ_PQ;
constexpr size_t OFF_CWT   = OFF_Q + SZ_PQ;                // cwT [k][i48][o32]
constexpr size_t SZ_CWT    = (size_t)CORR * CIN * 32;      // 23,040
constexpr size_t OFF_W0R   = OFF_CWT + SZ_CWT;             // W0r [cf512][o64]
constexpr size_t SZ_W0R    = 512 * 64;
constexpr size_t OFF_H     = OFF_W0R + SZ_W0R;             // h [b][n][512]
constexpr size_t SZ_H      = (size_t)B * M1 * 512;
constexpr size_t OFF_PREVT = OFF_H + SZ_H;                 // prevT [b][n][16]
constexpr size_t SZ_PREVT  = (size_t)B * NPTS * 16;
constexpr size_t OFF_CNT   = OFF_PREVT + SZ_PREVT;         // counts (int)
constexpr size_t OFF_OFFS  = OFF_CNT + NSCAN;              // offsets (int)
constexpr size_t OFF_CURS  = OFF_OFFS + NSCAN;             // cursors (int)
constexpr size_t OFF_REC   = OFF_CURS + NSCAN;             // rec (int)
constexpr size_t OFF_GT    = OFF_REC + NPAIR;              // gT (int) [b*M1][240]
// total ~11.2M floats ~= 45 MB

__device__ __forceinline__ float leaky(float v) { return v > 0.f ? v : NEG * v; }

// ============ fused prep: slot counting + prev transpose + weight prep ============
__global__ __launch_bounds__(256) void k_pre(const int* __restrict__ lo,
                                             const float* __restrict__ prev,
                                             const float* __restrict__ cw0,
                                             const float* __restrict__ bw0,
                                             int* __restrict__ counts,
                                             float* __restrict__ prevT,
                                             float* __restrict__ cwT,
                                             float* __restrict__ W0r) {
  int bx = blockIdx.x, tid = threadIdx.x;
  if (bx < 512) {                       // count pass
    int t = bx * 256 + tid;
    int slot = lo[t] + 1;
    atomicAdd(counts + slot, 1);
  } else if (bx < 1024) {               // prev transpose [b][16][N] -> [b][n][16]
    __shared__ float tile[16][65];
    int bb = bx - 512;
    int b = bb >> 8, n0 = (bb & 255) * 64;
    for (int e = tid; e < 1024; e += 256) {
      int ln = e & 63, r = e >> 6;
      tile[r][ln] = prev[((size_t)b * PREVC + r) * NPTS + n0 + ln];
    }
    __syncthreads();
    for (int e = tid; e < 1024; e += 256) {
      int c = e & 15, nn = e >> 4;
      prevT[((size_t)b * NPTS + n0 + nn) * 16 + c] = tile[c][nn];
    }
  } else {                              // weight prep
    int e = (bx - 1024) * 256 + tid;
    if (e < CORR * CIN * 32) {
      int o = e & 31, i = (e >> 5) % CIN, k = e / (CIN * 32);
      cwT[e] = cw0[((size_t)o * CIN + i) * CORR + k];
    }
    int e2 = e - CORR * CIN * 32;
    if (e2 >= 0 && e2 < 512 * 64) {
      int o3 = e2 & 63, cf = e2 >> 6, c = cf >> 4, f = cf & 15;
      W0r[e2] = (f < FILT) ? bw0[((size_t)o3 * CO0 + c) * FILT + f] : 0.f;
    }
  }
}

// ============ single-wave exclusive scan over counts ============
__global__ void k_scan(const int* __restrict__ counts, int* __restrict__ offsets,
                       int* __restrict__ cursors) {
  int lane = threadIdx.x;  // 64 threads
  int carry = 0;
  for (int c0 = 0; c0 < NSCAN; c0 += 64) {
    int v = counts[c0 + lane];
    int orig = v;
#pragma unroll
    for (int s = 1; s < 64; s <<= 1) {
      int t = __shfl_up(v, s);
      if (lane >= s) v += t;
    }
    int excl = carry + v - orig;
    offsets[c0 + lane] = excl;
    cursors[c0 + lane] = excl;
    carry += __shfl(v, 63);
  }
}

// ============ scatter pair ids into slot-sorted order ============
__global__ void k_scatter(const int* __restrict__ lo, int* __restrict__ cursors,
                          int* __restrict__ rec) {
  int t = blockIdx.x * 256 + threadIdx.x;
  int slot = lo[t] + 1;
  int pos = atomicAdd(cursors + slot, 1);
  rec[pos] = t;
}

// ============ per-slot summation + normalize + feat fills ============
__global__ __launch_bounds__(256) void k_sum(const int* __restrict__ rec,
                                             const int* __restrict__ offsets,
                                             const float* __restrict__ bary,
                                             const float* __restrict__ prevT,
                                             const float* __restrict__ feat1,
                                             const float* __restrict__ feat2,
                                             float* __restrict__ splat1,
                                             float* __restrict__ splat2) {
  int tid = threadIdx.x;
  int s = blockIdx.x * 4 + (tid >> 6);
  if (s >= NSLOT) return;
  int lane = tid & 63, c = lane & 15, g = lane >> 4;
  int start = offsets[s], end = offsets[s + 1];
  float acc = 0.f, wsum = 0.f;
  for (int e = start + g; e < end; e += 4) {
    int t = rec[e];
    float w = bary[t];
    int n = t % NPTS;
    int b = t / (D1 * NPTS);
    acc += w * prevT[((size_t)b * NPTS + n) * 16 + c];
    wsum += w;
  }
  acc  += __shfl_down(acc, 32);  acc  += __shfl_down(acc, 16);
  wsum += __shfl_down(wsum, 32); wsum += __shfl_down(wsum, 16);
  if (lane < 16) {
    int m = s % MS, b2 = s / MS;
    float scale = 1.f / (wsum + 1e-5f);
    splat1[(size_t)s * 32 + c] = acc * scale;
    float f1 = (m == 0) ? 0.f : feat1[((size_t)b2 * C + c) * M1 + (m - 1)];
    splat1[(size_t)s * 32 + 16 + c] = f1;
    float f2 = (m == 0) ? 0.f : feat2[((size_t)b2 * C + c) * M1 + (m - 1)];
    splat2[(size_t)s * 16 + c] = f2;
  }
}

// ============ transpose pc1/pc2 -> per-point record gT[b*M1+n][240] (+1 folded) ============
__global__ __launch_bounds__(256) void k_tpose(const int* __restrict__ pc1,
                                               const int* __restrict__ pc2,
                                               int* __restrict__ gT) {
  int b = blockIdx.z & 1, which = blockIdx.z >> 1;
  const int* src;
  int R, doff;
  if (which == 0) { src = pc2 + (size_t)b * FILT * CORR * M1; R = FILT * CORR; doff = 0; }
  else            { src = pc1 + (size_t)b * CORR * M1;        R = CORR;        doff = 225; }
  int r0 = blockIdx.y * 16;
  if (r0 >= R) return;
  int n0 = blockIdx.x * 64;
  int nr = min(16, R - r0);
  __shared__ int tile[16][65];
  int tid = threadIdx.x;
  for (int e = tid; e < nr * 64; e += 256) {
    int ln = e & 63, r = e >> 6;
    tile[r][ln] = src[(size_t)(r0 + r) * M1 + n0 + ln] + 1;
  }
  __syncthreads();
  for (int e = tid; e < 1024; e += 256) {
    int rr = e & 15, nn = e >> 4;
    if (rr < nr)
      gT[((size_t)b * M1 + n0 + nn) * GSTR + doff + r0 + rr] = tile[rr][nn];
  }
}

// ============ per-slot projections P, Q (bf16 out) ============
// Q[b][k][m][o] = sum_{i<32} splat1[m][i]*cw0[o][i][k];  P: i<16 over splat2 w/ cw0[o][32+i][k]
__global__ __launch_bounds__(256) void k_pq(const float* __restrict__ sp1,
                                            const float* __restrict__ sp2,
                                            const float* __restrict__ cwT,
                                            __hip_bfloat16* __restrict__ Pt,
                                            __hip_bfloat16* __restrict__ Qt) {
  __shared__ float wk[CIN][33];
  int k = blockIdx.y, b = blockIdx.z;
  int tid = threadIdx.x;
  int m = blockIdx.x * 16 + (tid >> 4);
  int o2 = tid & 15;
  for (int e = tid; e < CIN * 32; e += 256)
    wk[e >> 5][e & 31] = cwT[(size_t)k * CIN * 32 + e];
  __syncthreads();
  if (m >= MS) return;
  const float* s1 = sp1 + ((size_t)b * MS + m) * 32;
  const float* s2 = sp2 + ((size_t)b * MS + m) * 16;
  int oa = o2 * 2, ob = oa + 1;
  float q0 = 0, q1 = 0, p0 = 0, p1 = 0;
#pragma unroll
  for (int i4 = 0; i4 < 8; ++i4) {
    float4 s = *(const float4*)(s1 + i4 * 4);
    q0 += s.x * wk[i4*4+0][oa] + s.y * wk[i4*4+1][oa] + s.z * wk[i4*4+2][oa] + s.w * wk[i4*4+3][oa];
    q1 += s.x * wk[i4*4+0][ob] + s.y * wk[i4*4+1][ob] + s.z * wk[i4*4+2][ob] + s.w * wk[i4*4+3][ob];
  }
#pragma unroll
  for (int i4 = 0; i4 < 4; ++i4) {
    float4 s = *(const float4*)(s2 + i4 * 4);
    p0 += s.x * wk[32+i4*4+0][oa] + s.y * wk[32+i4*4+1][oa] + s.z * wk[32+i4*4+2][oa] + s.w * wk[32+i4*4+3][oa];
    p1 += s.x * wk[32+i4*4+0][ob] + s.y * wk[32+i4*4+1][ob] + s.z * wk[32+i4*4+2][ob] + s.w * wk[32+i4*4+3][ob];
  }
  size_t base = ((size_t)(b * CORR + k) * MS + m) * 32;
  __hip_bfloat162 qq, pp;
  qq.x = __float2bfloat16(q0); qq.y = __float2bfloat16(q1);
  pp.x = __float2bfloat16(p0); pp.y = __float2bfloat16(p1);
  *reinterpret_cast<__hip_bfloat162*>(Qt + base + oa) = qq;
  *reinterpret_cast<__hip_bfloat162*>(Pt + base + oa) = pp;
}

// ============ gather + corr-conv (both layers) ============
__global__ __launch_bounds__(512) void k_gather(const __hip_bfloat16* __restrict__ Pt,
                                                const __hip_bfloat16* __restrict__ Qt,
                                                const int* __restrict__ gT,
                                                const float* __restrict__ cw1,
                                                const float* __restrict__ cb0,
                                                const float* __restrict__ cb1,
                                                float* __restrict__ hbuf) {
  __shared__ int   idxs[GSTR];
  __shared__ float p1s[32];
  __shared__ float xls[CORR][36];
  __shared__ float hT[32 * 17];

  int bid = blockIdx.x;                 // == b*M1 + n
  int b = bid >> 12;
  int tid = threadIdx.x;
  int o = tid & 31, f = tid >> 5;

  if (tid < GSTR) idxs[tid] = gT[(size_t)bid * GSTR + tid];

  float wreg[32];
#pragma unroll
  for (int c4 = 0; c4 < 8; ++c4) {
    float4 w = *(const float4*)(cw1 + o * CO0 + c4 * 4);
    wreg[c4*4+0] = w.x; wreg[c4*4+1] = w.y; wreg[c4*4+2] = w.z; wreg[c4*4+3] = w.w;
  }
  __syncthreads();

  float acc = 0.f;
  if (f < CORR) {
    const __hip_bfloat16* Pb = Pt + (size_t)b * CORR * MS * 32;
#pragma unroll
    for (int k = 0; k < CORR; ++k)
      acc += __bfloat162float(Pb[((size_t)k * MS + idxs[f * CORR + k]) * 32 + o]);
  } else {
    const __hip_bfloat16* Qb = Qt + (size_t)b * CORR * MS * 32;
    float p = 0.f;
#pragma unroll
    for (int k = 0; k < CORR; ++k)
      p += __bfloat162float(Qb[((size_t)k * MS + idxs[225 + k]) * 32 + o]);
    p1s[o] = p;
  }
  __syncthreads();

  if (f < CORR) {
    float x = acc + p1s[o] + cb0[o];
    xls[f][o] = leaky(x);
  }
  __syncthreads();

  if (f < CORR) {
    float h = cb1[o];
#pragma unroll
    for (int c4 = 0; c4 < 8; ++c4) {
      float4 xv = *(const float4*)(&xls[f][c4 * 4]);
      h += wreg[c4*4+0]*xv.x + wreg[c4*4+1]*xv.y + wreg[c4*4+2]*xv.z + wreg[c4*4+3]*xv.w;
    }
    hT[o * 17 + f] = leaky(h);
  } else {
    hT[o * 17 + 15] = 0.f;
  }
  __syncthreads();

  hbuf[(size_t)bid * 512 + tid] = hT[(tid >> 4) * 17 + (tid & 15)];
}

// ============ blur conv ============
__global__ __launch_bounds__(256) void k_blur(const float* __restrict__ hbuf,
                                              const float* __restrict__ W0r,
                                              const float* __restrict__ bb0,
                                              const float* __restrict__ bw1,
                                              const float* __restrict__ bb1,
                                              float* __restrict__ out) {
  __shared__ float hs[64][33];
  __shared__ float ws[64][68];
  __shared__ float y0s[64][36];

  int bid = blockIdx.x;
  int b = bid >> 7;
  int n0 = (bid & 127) * 32;
  int tid = threadIdx.x;
  int og = tid & 15, ng = tid >> 4;

  float acc[4][2] = {};
  for (int kc = 0; kc < 512; kc += 64) {
    __syncthreads();
    for (int e = tid; e < 512; e += 256) {
      int nn = e >> 4, k4 = e & 15;
      float4 v = *(const float4*)(hbuf + ((size_t)b * M1 + n0 + nn) * 512 + kc + k4 * 4);
      hs[k4*4+0][nn] = v.x; hs[k4*4+1][nn] = v.y; hs[k4*4+2][nn] = v.z; hs[k4*4+3][nn] = v.w;
    }
    for (int e = tid; e < 1024; e += 256) {
      int row = e >> 4, c4 = e & 15;
      *(float4*)&ws[row][c4 * 4] = *(const float4*)(W0r + (size_t)(kc + row) * 64 + c4 * 4);
    }
    __syncthreads();
#pragma unroll 16
    for (int kk = 0; kk < 64; ++kk) {
      float4 w = *(const float4*)&ws[kk][og * 4];
      float h0 = hs[kk][ng * 2], h1 = hs[kk][ng * 2 + 1];
      acc[0][0] += w.x * h0; acc[0][1] += w.x * h1;
      acc[1][0] += w.y * h0; acc[1][1] += w.y * h1;
      acc[2][0] += w.z * h0; acc[2][1] += w.z * h1;
      acc[3][0] += w.w * h0; acc[3][1] += w.w * h1;
    }
  }
  __syncthreads();

#pragma unroll
  for (int i = 0; i < 4; ++i) {
    int o3 = og * 4 + i;
    float bias = bb0[o3];
#pragma unroll
    for (int j = 0; j < 2; ++j)
      y0s[o3][ng * 2 + j] = leaky(acc[i][j] + bias);
  }
  for (int e = tid; e < 64 * 64; e += 256) {
    int o1e = e >> 6, c = e & 63;
    ws[c][o1e] = bw1[e];
  }
  __syncthreads();

  int o1 = tid & 63, ng4 = tid >> 6;
  float a8[8] = {};
  for (int c = 0; c < 64; ++c) {
    float w = ws[c][o1];
    float4 ya = *(const float4*)&y0s[c][ng4 * 8];
    float4 yb = *(const float4*)&y0s[c][ng4 * 8 + 4];
    a8[0] += w * ya.x; a8[1] += w * ya.y; a8[2] += w * ya.z; a8[3] += w * ya.w;
    a8[4] += w * yb.x; a8[5] += w * yb.y; a8[6] += w * yb.z; a8[7] += w * yb.w;
  }
  float bias = bb1[o1];
#pragma unroll
  for (int j = 0; j < 8; ++j)
    out[((size_t)b * O1 + o1) * M1 + n0 + ng4 * 8 + j] = a8[j] + bias;
}

}  // namespace

extern "C" void kernel_launch(void* const* d_in, const int* in_sizes, int n_in,
                              void* d_out, int out_size, void* d_ws, size_t ws_size,
                              hipStream_t stream) {
  const float* feat1 = (const float*)d_in[0];
  const float* feat2 = (const float*)d_in[1];
  const float* prev  = (const float*)d_in[2];
  const float* bary  = (const float*)d_in[3];
  const float* cw0   = (const float*)d_in[4];
  const float* cb0   = (const float*)d_in[5];
  const float* cw1   = (const float*)d_in[6];
  const float* cb1   = (const float*)d_in[7];
  const float* bw0   = (const float*)d_in[8];
  const float* bb0   = (const float*)d_in[9];
  const float* bw1   = (const float*)d_in[10];
  const float* bb1   = (const float*)d_in[11];
  const int* lo  = (const int*)d_in[12];
  const int* pc1 = (const int*)d_in[13];
  const int* pc2 = (const int*)d_in[14];

  float* ws = (float*)d_ws;
  float* splat1 = ws + OFF_SP1;
  float* splat2 = ws + OFF_SP2;
  __hip_bfloat16* Pt = (__hip_bfloat16*)(ws + OFF_P);
  __hip_bfloat16* Qt = (__hip_bfloat16*)(ws + OFF_Q);
  float* cwT   = ws + OFF_CWT;
  float* W0r   = ws + OFF_W0R;
  float* hbuf  = ws + OFF_H;
  float* prevT = ws + OFF_PREVT;
  int* counts  = (int*)(ws + OFF_CNT);
  int* offsets = (int*)(ws + OFF_OFFS);
  int* cursors = (int*)(ws + OFF_CURS);
  int* rec     = (int*)(ws + OFF_REC);
  int* gT      = (int*)(ws + OFF_GT);
  float* out   = (float*)d_out;

  hipMemsetAsync(counts, 0, NSCAN * sizeof(int), stream);

  hipLaunchKernelGGL(k_pre, dim3(1243), dim3(256), 0, stream,
                     lo, prev, cw0, bw0, counts, prevT, cwT, W0r);
  hipLaunchKernelGGL(k_tpose, dim3(64, 15, 4), dim3(256), 0, stream, pc1, pc2, gT);
  hipLaunchKernelGGL(k_scan, dim3(1), dim3(64), 0, stream, counts, offsets, cursors);
  hipLaunchKernelGGL(k_scatter, dim3(NPAIR / 256), dim3(256), 0, stream, lo, cursors, rec);
  hipLaunchKernelGGL(k_sum, dim3((NSLOT + 3) / 4), dim3(256), 0, stream,
                     rec, offsets, bary, prevT, feat1, feat2, splat1, splat2);
  hipLaunchKernelGGL(k_pq, dim3((MS + 15) / 16, CORR, B), dim3(256), 0, stream,
                     splat1, splat2, cwT, Pt, Qt);
  hipLaunchKernelGGL(k_gather, dim3(B * M1), dim3(512), 0, stream,
                     Pt, Qt, gT, cw1, cb0, cb1, hbuf);
  hipLaunchKernelGGL(k_blur, dim3(B * M1 / 32), dim3(256), 0, stream,
                     hbuf, W0r, bb0, bw1, bb1, out);
}

// Round 4
// 134.623 us; speedup vs baseline: 3.6854x; 1.5061x over previous
//
#include <hip/hip_runtime.h>
#include <hip/hip_bf16.h>

namespace {

constexpr int B     = 2;
constexpr int C     = 16;
constexpr int PREVC = 16;
constexpr int NPTS  = 16384;
constexpr int M1    = 4096;
constexpr int D1    = 4;
constexpr int CORR  = 15;
constexpr int FILT  = 15;
constexpr int CIN   = 48;
constexpr int CO0   = 32;
constexpr int O1    = 64;
constexpr int MS    = M1 + 1;        // 4097
constexpr int NSLOT = B * MS;        // 8194
constexpr int NPAIR = B * D1 * NPTS; // 131072
constexpr int NSCAN = 9216;          // 1024 * 9 >= NSLOT+1
constexpr int GSTR  = 240;           // 225 idx2 + 15 idx1 (ushort, +1 folded)
constexpr float NEG = 0.1f;

// ---- workspace layout (float units) ----
constexpr size_t OFF_SP1   = 0;                               // splat1 [slot][32] f32
constexpr size_t SZ_SP1    = (size_t)NSLOT * 32;
constexpr size_t OFF_SP2   = OFF_SP1 + SZ_SP1;                // splat2 [slot][16] f32
constexpr size_t SZ_SP2    = (size_t)NSLOT * 16;
constexpr size_t OFF_P     = OFF_SP2 + SZ_SP2;                // P bf16 [b][k][m][32]
constexpr size_t SZ_PQ     = (size_t)B * CORR * MS * 32 / 2;
constexpr size_t OFF_Q     = OFF_P + SZ_PQ;                   // Q bf16
constexpr size_t OFF_CWT   = OFF_Q + SZ_PQ;                   // cwT [k][i48][o32] f32
constexpr size_t SZ_CWT    = (size_t)CORR * CIN * 32;
constexpr size_t OFF_W0R   = OFF_CWT + SZ_CWT;                // W0r [cf512][o64] f32
constexpr size_t SZ_W0R    = 512 * 64;
constexpr size_t OFF_H     = OFF_W0R + SZ_W0R;                // h bf16 [b][n][512]
constexpr size_t SZ_H      = (size_t)B * M1 * 512 / 2;
constexpr size_t OFF_PREVT = OFF_H + SZ_H;                    // prevT [b][n][16] f32
constexpr size_t SZ_PREVT  = (size_t)B * NPTS * 16;
constexpr size_t OFF_CNT   = OFF_PREVT + SZ_PREVT;            // counts (int)
constexpr size_t OFF_OFFS  = OFF_CNT + NSCAN;                 // offsets (int)
constexpr size_t OFF_CURS  = OFF_OFFS + NSCAN;                // cursors (int)
constexpr size_t OFF_REC   = OFF_CURS + NSCAN;                // rec (int)
constexpr size_t OFF_GT    = OFF_REC + NPAIR;                 // gT (ushort) [b*M1][240]
constexpr size_t SZ_GT     = (size_t)B * M1 * GSTR / 2;

__device__ __forceinline__ float leaky(float v) { return v > 0.f ? v : NEG * v; }

// ============ fused prep: count + prev transpose + weight prep + pc transpose ============
__global__ __launch_bounds__(256) void k_pre(const int* __restrict__ lo,
                                             const float* __restrict__ prev,
                                             const float* __restrict__ cw0,
                                             const float* __restrict__ bw0,
                                             const int* __restrict__ pc1,
                                             const int* __restrict__ pc2,
                                             int* __restrict__ counts,
                                             float* __restrict__ prevT,
                                             float* __restrict__ cwT,
                                             float* __restrict__ W0r,
                                             unsigned short* __restrict__ gT) {
  int bx = blockIdx.x, tid = threadIdx.x;
  if (bx < 512) {                       // ---- count pass ----
    int t = bx * 256 + tid;
    int slot = lo[t] + 1;
    atomicAdd(counts + slot, 1);
  } else if (bx < 1024) {               // ---- prev transpose [b][16][N] -> [b][n][16] ----
    __shared__ float tile[16][65];
    int bb = bx - 512;
    int b = bb >> 8, n0 = (bb & 255) * 64;
    for (int e = tid; e < 1024; e += 256) {
      int ln = e & 63, r = e >> 6;
      tile[r][ln] = prev[((size_t)b * PREVC + r) * NPTS + n0 + ln];
    }
    __syncthreads();
    for (int e = tid; e < 1024; e += 256) {
      int c = e & 15, nn = e >> 4;
      prevT[((size_t)b * NPTS + n0 + nn) * 16 + c] = tile[c][nn];
    }
  } else if (bx < 1243) {               // ---- weight prep ----
    int e = (bx - 1024) * 256 + tid;
    if (e < CORR * CIN * 32) {
      int o = e & 31, i = (e >> 5) % CIN, k = e / (CIN * 32);
      cwT[e] = cw0[((size_t)o * CIN + i) * CORR + k];
    }
    int e2 = e - CORR * CIN * 32;
    if (e2 >= 0 && e2 < 512 * 64) {
      int o3 = e2 & 63, cf = e2 >> 6, c = cf >> 4, f = cf & 15;
      W0r[e2] = (f < FILT) ? bw0[((size_t)o3 * CO0 + c) * FILT + f] : 0.f;
    }
  } else {                              // ---- pc1/pc2 transpose -> gT (ushort, +1) ----
    __shared__ int tile[16][65];
    int t = bx - 1243;
    int n0 = (t & 63) * 64;
    int rest = t >> 6;                  // 0..31
    int b = rest & 1;
    int rt = rest >> 1;                 // 0..15
    const int* src; int r0, nr, doff;
    if (rt < 15) { src = pc2 + (size_t)b * FILT * CORR * M1; r0 = rt * 16;
                   nr = min(16, FILT * CORR - r0); doff = 0; }
    else         { src = pc1 + (size_t)b * CORR * M1; r0 = 0; nr = CORR; doff = 225; }
    for (int e = tid; e < nr * 64; e += 256) {
      int ln = e & 63, r = e >> 6;
      tile[r][ln] = src[(size_t)(r0 + r) * M1 + n0 + ln] + 1;
    }
    __syncthreads();
    for (int e = tid; e < 1024; e += 256) {
      int rr = e & 15, nn = e >> 4;
      if (rr < nr)
        gT[((size_t)b * M1 + n0 + nn) * GSTR + doff + r0 + rr] =
            (unsigned short)tile[rr][nn];
    }
  }
}

// ============ parallel exclusive scan (one 1024-thread block) ============
__global__ __launch_bounds__(1024) void k_scan(const int* __restrict__ counts,
                                               int* __restrict__ offsets,
                                               int* __restrict__ cursors) {
  __shared__ int wsum[16];
  int t = threadIdx.x;
  int base = t * 9;
  int v[9];
  int s = 0;
#pragma unroll
  for (int i = 0; i < 9; ++i) { v[i] = counts[base + i]; s += v[i]; }
  int lane = t & 63, w = t >> 6;
  int ps = s;
#pragma unroll
  for (int d = 1; d < 64; d <<= 1) {
    int u = __shfl_up(ps, d);
    if (lane >= d) ps += u;
  }
  if (lane == 63) wsum[w] = ps;
  __syncthreads();
  if (w == 0 && lane < 16) {
    int x = wsum[lane];
#pragma unroll
    for (int d = 1; d < 16; d <<= 1) {
      int u = __shfl_up(x, d);
      if (lane >= d) x += u;
    }
    wsum[lane] = x;  // inclusive wave sums
  }
  __syncthreads();
  int excl = ps - s + (w > 0 ? wsum[w - 1] : 0);
#pragma unroll
  for (int i = 0; i < 9; ++i) {
    int idx = base + i;
    offsets[idx] = excl;
    cursors[idx] = excl;
    excl += v[i];
  }
}

// ============ scatter pair ids into slot-sorted order ============
__global__ void k_scatter(const int* __restrict__ lo, int* __restrict__ cursors,
                          int* __restrict__ rec) {
  int t = blockIdx.x * 256 + threadIdx.x;
  int slot = lo[t] + 1;
  int pos = atomicAdd(cursors + slot, 1);
  rec[pos] = t;
}

// ============ per-slot summation + normalize + feat fills ============
__global__ __launch_bounds__(256) void k_sum(const int* __restrict__ rec,
                                             const int* __restrict__ offsets,
                                             const float* __restrict__ bary,
                                             const float* __restrict__ prevT,
                                             const float* __restrict__ feat1,
                                             const float* __restrict__ feat2,
                                             float* __restrict__ splat1,
                                             float* __restrict__ splat2) {
  int tid = threadIdx.x;
  int s = blockIdx.x * 4 + (tid >> 6);
  if (s >= NSLOT) return;
  int lane = tid & 63, c = lane & 15, g = lane >> 4;
  int start = offsets[s], end = offsets[s + 1];
  float acc = 0.f, wsum = 0.f;
  for (int e = start + g; e < end; e += 4) {
    int t = rec[e];
    float w = bary[t];
    int n = t % NPTS;
    int b = t / (D1 * NPTS);
    acc += w * prevT[((size_t)b * NPTS + n) * 16 + c];
    wsum += w;
  }
  acc  += __shfl_down(acc, 32);  acc  += __shfl_down(acc, 16);
  wsum += __shfl_down(wsum, 32); wsum += __shfl_down(wsum, 16);
  if (lane < 16) {
    int m = s % MS, b2 = s / MS;
    float scale = 1.f / (wsum + 1e-5f);
    splat1[(size_t)s * 32 + c] = acc * scale;
    float f1 = (m == 0) ? 0.f : feat1[((size_t)b2 * C + c) * M1 + (m - 1)];
    splat1[(size_t)s * 32 + 16 + c] = f1;
    float f2 = (m == 0) ? 0.f : feat2[((size_t)b2 * C + c) * M1 + (m - 1)];
    splat2[(size_t)s * 16 + c] = f2;
  }
}

// ============ per-slot projections P, Q (bf16 out) ============
__global__ __launch_bounds__(256) void k_pq(const float* __restrict__ sp1,
                                            const float* __restrict__ sp2,
                                            const float* __restrict__ cwT,
                                            __hip_bfloat16* __restrict__ Pt,
                                            __hip_bfloat16* __restrict__ Qt) {
  __shared__ float wk[CIN][33];
  int k = blockIdx.y, b = blockIdx.z;
  int tid = threadIdx.x;
  int m = blockIdx.x * 16 + (tid >> 4);
  int o2 = tid & 15;
  for (int e = tid; e < CIN * 32; e += 256)
    wk[e >> 5][e & 31] = cwT[(size_t)k * CIN * 32 + e];
  __syncthreads();
  if (m >= MS) return;
  const float* s1 = sp1 + ((size_t)b * MS + m) * 32;
  const float* s2 = sp2 + ((size_t)b * MS + m) * 16;
  int oa = o2 * 2, ob = oa + 1;
  float q0 = 0, q1 = 0, p0 = 0, p1 = 0;
#pragma unroll
  for (int i4 = 0; i4 < 8; ++i4) {
    float4 s = *(const float4*)(s1 + i4 * 4);
    q0 += s.x * wk[i4*4+0][oa] + s.y * wk[i4*4+1][oa] + s.z * wk[i4*4+2][oa] + s.w * wk[i4*4+3][oa];
    q1 += s.x * wk[i4*4+0][ob] + s.y * wk[i4*4+1][ob] + s.z * wk[i4*4+2][ob] + s.w * wk[i4*4+3][ob];
  }
#pragma unroll
  for (int i4 = 0; i4 < 4; ++i4) {
    float4 s = *(const float4*)(s2 + i4 * 4);
    p0 += s.x * wk[32+i4*4+0][oa] + s.y * wk[32+i4*4+1][oa] + s.z * wk[32+i4*4+2][oa] + s.w * wk[32+i4*4+3][oa];
    p1 += s.x * wk[32+i4*4+0][ob] + s.y * wk[32+i4*4+1][ob] + s.z * wk[32+i4*4+2][ob] + s.w * wk[32+i4*4+3][ob];
  }
  size_t base = ((size_t)(b * CORR + k) * MS + m) * 32;
  __hip_bfloat162 qq, pp;
  qq.x = __float2bfloat16(q0); qq.y = __float2bfloat16(q1);
  pp.x = __float2bfloat16(p0); pp.y = __float2bfloat16(p1);
  *reinterpret_cast<__hip_bfloat162*>(Qt + base + oa) = qq;
  *reinterpret_cast<__hip_bfloat162*>(Pt + base + oa) = pp;
}

// ============ gather + corr-conv; 256 thr = (o:32) x (fg:8), 2 f's per thread ============
// XCD batch swizzle: XCDs 0-3 process b=0, XCDs 4-7 b=1 (assumes bid%8 round-robin)
__global__ __launch_bounds__(256) void k_gather(const __hip_bfloat16* __restrict__ Pt,
                                                const __hip_bfloat16* __restrict__ Qt,
                                                const unsigned short* __restrict__ gT,
                                                const float* __restrict__ cw1,
                                                const float* __restrict__ cb0,
                                                const float* __restrict__ cb1,
                                                __hip_bfloat16* __restrict__ hbuf) {
  __shared__ unsigned short idxs[GSTR];
  __shared__ float p1s[32];
  __shared__ float cw1T[32][33];
  __shared__ float xls[16][36];
  __shared__ float hT[32 * 17];

  int bid = blockIdx.x;
  int b = (bid >> 2) & 1;
  int n = ((bid & 3) << 10) | (bid >> 3);
  int pt = (b << 12) | n;              // b*M1 + n
  int tid = threadIdx.x;
  int o = tid & 31, fg = tid >> 5;     // fg in [0,8)

  if (tid < GSTR) idxs[tid] = gT[(size_t)pt * GSTR + tid];
  {
    int oo = tid >> 3, c0 = (tid & 7) * 4;
    float4 wv = *(const float4*)(cw1 + oo * CO0 + c0);
    cw1T[c0+0][oo] = wv.x; cw1T[c0+1][oo] = wv.y;
    cw1T[c0+2][oo] = wv.z; cw1T[c0+3][oo] = wv.w;
  }
  __syncthreads();

  const __hip_bfloat16* Pb = Pt + (size_t)b * CORR * MS * 32;
  const __hip_bfloat16* Qb = Qt + (size_t)b * CORR * MS * 32;
  float acc0 = 0.f, acc1 = 0.f;
#pragma unroll
  for (int k = 0; k < CORR; ++k)
    acc0 += __bfloat162float(Pb[((size_t)k * MS + idxs[fg * CORR + k]) * 32 + o]);
  if (fg < 7) {
#pragma unroll
    for (int k = 0; k < CORR; ++k)
      acc1 += __bfloat162float(Pb[((size_t)k * MS + idxs[(fg + 8) * CORR + k]) * 32 + o]);
  } else {
#pragma unroll
    for (int k = 0; k < CORR; ++k)
      acc1 += __bfloat162float(Qb[((size_t)k * MS + idxs[225 + k]) * 32 + o]);
    p1s[o] = acc1;
  }
  __syncthreads();

  float p1 = p1s[o] + cb0[o];
  xls[fg][o] = leaky(acc0 + p1);
  if (fg < 7) xls[fg + 8][o] = leaky(acc1 + p1);
  __syncthreads();

  float h0 = cb1[o], h1 = cb1[o];
#pragma unroll
  for (int c = 0; c < 32; ++c) {
    float w = cw1T[c][o];
    h0 += w * xls[fg][c];
    if (fg < 7) h1 += w * xls[fg + 8][c];
  }
  hT[o * 17 + fg] = leaky(h0);
  if (fg < 7) hT[o * 17 + fg + 8] = leaky(h1);
  else        hT[o * 17 + 15] = 0.f;
  __syncthreads();

  int cf0 = tid * 2;
  int oo = cf0 >> 4, ff = cf0 & 15;
  __hip_bfloat162 hv;
  hv.x = __float2bfloat16(hT[oo * 17 + ff]);
  hv.y = __float2bfloat16(hT[oo * 17 + ff + 1]);
  *reinterpret_cast<__hip_bfloat162*>(hbuf + (size_t)pt * 512 + cf0) = hv;
}

// ============ blur conv ============
__global__ __launch_bounds__(256) void k_blur(const __hip_bfloat16* __restrict__ hbuf,
                                              const float* __restrict__ W0r,
                                              const float* __restrict__ bb0,
                                              const float* __restrict__ bw1,
                                              const float* __restrict__ bb1,
                                              float* __restrict__ out) {
  __shared__ float hs[64][33];
  __shared__ float ws[64][68];
  __shared__ float y0s[64][36];

  int bid = blockIdx.x;
  int b = bid >> 7;
  int n0 = (bid & 127) * 32;
  int tid = threadIdx.x;
  int og = tid & 15, ng = tid >> 4;

  float acc[4][2] = {};
  for (int kc = 0; kc < 512; kc += 64) {
    __syncthreads();
    {   // stage h chunk (bf16 -> f32), transposed: hs[kk][nn]
      int nn = tid >> 3, k8 = tid & 7;
      const __hip_bfloat16* hp = hbuf + ((size_t)b * M1 + n0 + nn) * 512 + kc + k8 * 8;
#pragma unroll
      for (int j = 0; j < 4; ++j) {
        __hip_bfloat162 v2 = *(const __hip_bfloat162*)(hp + j * 2);
        hs[k8 * 8 + j * 2 + 0][nn] = __bfloat162float(v2.x);
        hs[k8 * 8 + j * 2 + 1][nn] = __bfloat162float(v2.y);
      }
    }
    for (int e = tid; e < 1024; e += 256) {
      int row = e >> 4, c4 = e & 15;
      *(float4*)&ws[row][c4 * 4] = *(const float4*)(W0r + (size_t)(kc + row) * 64 + c4 * 4);
    }
    __syncthreads();
#pragma unroll 16
    for (int kk = 0; kk < 64; ++kk) {
      float4 w = *(const float4*)&ws[kk][og * 4];
      float h0 = hs[kk][ng * 2], h1 = hs[kk][ng * 2 + 1];
      acc[0][0] += w.x * h0; acc[0][1] += w.x * h1;
      acc[1][0] += w.y * h0; acc[1][1] += w.y * h1;
      acc[2][0] += w.z * h0; acc[2][1] += w.z * h1;
      acc[3][0] += w.w * h0; acc[3][1] += w.w * h1;
    }
  }
  __syncthreads();

#pragma unroll
  for (int i = 0; i < 4; ++i) {
    int o3 = og * 4 + i;
    float bias = bb0[o3];
#pragma unroll
    for (int j = 0; j < 2; ++j)
      y0s[o3][ng * 2 + j] = leaky(acc[i][j] + bias);
  }
  for (int e = tid; e < 64 * 64; e += 256) {
    int o1e = e >> 6, c = e & 63;
    ws[c][o1e] = bw1[e];
  }
  __syncthreads();

  int o1 = tid & 63, ng4 = tid >> 6;
  float a8[8] = {};
  for (int c = 0; c < 64; ++c) {
    float w = ws[c][o1];
    float4 ya = *(const float4*)&y0s[c][ng4 * 8];
    float4 yb = *(const float4*)&y0s[c][ng4 * 8 + 4];
    a8[0] += w * ya.x; a8[1] += w * ya.y; a8[2] += w * ya.z; a8[3] += w * ya.w;
    a8[4] += w * yb.x; a8[5] += w * yb.y; a8[6] += w * yb.z; a8[7] += w * yb.w;
  }
  float bias = bb1[o1];
#pragma unroll
  for (int j = 0; j < 8; ++j)
    out[((size_t)b * O1 + o1) * M1 + n0 + ng4 * 8 + j] = a8[j] + bias;
}

}  // namespace

extern "C" void kernel_launch(void* const* d_in, const int* in_sizes, int n_in,
                              void* d_out, int out_size, void* d_ws, size_t ws_size,
                              hipStream_t stream) {
  const float* feat1 = (const float*)d_in[0];
  const float* feat2 = (const float*)d_in[1];
  const float* prev  = (const float*)d_in[2];
  const float* bary  = (const float*)d_in[3];
  const float* cw0   = (const float*)d_in[4];
  const float* cb0   = (const float*)d_in[5];
  const float* cw1   = (const float*)d_in[6];
  const float* cb1   = (const float*)d_in[7];
  const float* bw0   = (const float*)d_in[8];
  const float* bb0   = (const float*)d_in[9];
  const float* bw1   = (const float*)d_in[10];
  const float* bb1   = (const float*)d_in[11];
  const int* lo  = (const int*)d_in[12];
  const int* pc1 = (const int*)d_in[13];
  const int* pc2 = (const int*)d_in[14];

  float* ws = (float*)d_ws;
  float* splat1 = ws + OFF_SP1;
  float* splat2 = ws + OFF_SP2;
  __hip_bfloat16* Pt = (__hip_bfloat16*)(ws + OFF_P);
  __hip_bfloat16* Qt = (__hip_bfloat16*)(ws + OFF_Q);
  float* cwT   = ws + OFF_CWT;
  float* W0r   = ws + OFF_W0R;
  __hip_bfloat16* hbuf = (__hip_bfloat16*)(ws + OFF_H);
  float* prevT = ws + OFF_PREVT;
  int* counts  = (int*)(ws + OFF_CNT);
  int* offsets = (int*)(ws + OFF_OFFS);
  int* cursors = (int*)(ws + OFF_CURS);
  int* rec     = (int*)(ws + OFF_REC);
  unsigned short* gT = (unsigned short*)(ws + OFF_GT);
  float* out   = (float*)d_out;

  hipMemsetAsync(counts, 0, NSCAN * sizeof(int), stream);

  hipLaunchKernelGGL(k_pre, dim3(1243 + 2048), dim3(256), 0, stream,
                     lo, prev, cw0, bw0, pc1, pc2, counts, prevT, cwT, W0r, gT);
  hipLaunchKernelGGL(k_scan, dim3(1), dim3(1024), 0, stream, counts, offsets, cursors);
  hipLaunchKernelGGL(k_scatter, dim3(NPAIR / 256), dim3(256), 0, stream, lo, cursors, rec);
  hipLaunchKernelGGL(k_sum, dim3((NSLOT + 3) / 4), dim3(256), 0, stream,
                     rec, offsets, bary, prevT, feat1, feat2, splat1, splat2);
  hipLaunchKernelGGL(k_pq, dim3((MS + 15) / 16, CORR, B), dim3(256), 0, stream,
                     splat1, splat2, cwT, Pt, Qt);
  hipLaunchKernelGGL(k_gather, dim3(B * M1), dim3(256), 0, stream,
                     Pt, Qt, gT, cw1, cb0, cb1, hbuf);
  hipLaunchKernelGGL(k_blur, dim3(B * M1 / 32), dim3(256), 0, stream,
                     hbuf, W0r, bb0, bw1, bb1, out);
}

// Round 5
// 128.811 us; speedup vs baseline: 3.8517x; 1.0451x over previous
//
#include <hip/hip_runtime.h>
#include <hip/hip_bf16.h>

namespace {

constexpr int B     = 2;
constexpr int C     = 16;
constexpr int PREVC = 16;
constexpr int NPTS  = 16384;
constexpr int M1    = 4096;
constexpr int D1    = 4;
constexpr int CORR  = 15;
constexpr int FILT  = 15;
constexpr int CIN   = 48;
constexpr int CO0   = 32;
constexpr int O1    = 64;
constexpr int MS    = M1 + 1;        // 4097
constexpr int NSLOT = B * MS;        // 8194
constexpr int NPAIR = B * D1 * NPTS; // 131072
constexpr int NSCAN = 9216;          // 1024 * 9 >= NSLOT+1
constexpr int GSTR  = 240;           // 225 idx2 + 15 idx1 (ushort, +1 folded)
constexpr float NEG = 0.1f;

// ---- workspace layout (float units) ----
constexpr size_t OFF_SP1   = 0;                               // splat1 [slot][32] f32
constexpr size_t SZ_SP1    = (size_t)NSLOT * 32;
constexpr size_t OFF_SP2   = OFF_SP1 + SZ_SP1;                // splat2 [slot][16] f32
constexpr size_t SZ_SP2    = (size_t)NSLOT * 16;
constexpr size_t OFF_P     = OFF_SP2 + SZ_SP2;                // P bf16 [b][k][m][32]
constexpr size_t SZ_PQ     = (size_t)B * CORR * MS * 32 / 2;
constexpr size_t OFF_Q     = OFF_P + SZ_PQ;                   // Q bf16
constexpr size_t OFF_CWT   = OFF_Q + SZ_PQ;                   // cwT [k][i48][o32] f32
constexpr size_t SZ_CWT    = (size_t)CORR * CIN * 32;
constexpr size_t OFF_W0R   = OFF_CWT + SZ_CWT;                // W0r [cf512][o64] f32
constexpr size_t SZ_W0R    = 512 * 64;
constexpr size_t OFF_H     = OFF_W0R + SZ_W0R;                // h bf16 [b][n][512]
constexpr size_t SZ_H      = (size_t)B * M1 * 512 / 2;
constexpr size_t OFF_PREVT = OFF_H + SZ_H;                    // prevT [b][n][16] f32
constexpr size_t SZ_PREVT  = (size_t)B * NPTS * 16;
constexpr size_t OFF_CNT   = OFF_PREVT + SZ_PREVT;            // counts (int)
constexpr size_t OFF_OFFS  = OFF_CNT + NSCAN;                 // offsets (int)
constexpr size_t OFF_CURS  = OFF_OFFS + NSCAN;                // cursors (int)
constexpr size_t OFF_REC   = OFF_CURS + NSCAN;                // rec (int)
constexpr size_t OFF_GT    = OFF_REC + NPAIR;                 // gT (ushort) [b*M1][240]
constexpr size_t SZ_GT     = (size_t)B * M1 * GSTR / 2;

__device__ __forceinline__ float leaky(float v) { return v > 0.f ? v : NEG * v; }

// ============ fused prep: count + prev transpose + weight prep + pc transpose ============
__global__ __launch_bounds__(256) void k_pre(const int* __restrict__ lo,
                                             const float* __restrict__ prev,
                                             const float* __restrict__ cw0,
                                             const float* __restrict__ bw0,
                                             const int* __restrict__ pc1,
                                             const int* __restrict__ pc2,
                                             int* __restrict__ counts,
                                             float* __restrict__ prevT,
                                             float* __restrict__ cwT,
                                             float* __restrict__ W0r,
                                             unsigned short* __restrict__ gT) {
  int bx = blockIdx.x, tid = threadIdx.x;
  if (bx < 512) {                       // ---- count pass ----
    int t = bx * 256 + tid;
    int slot = lo[t] + 1;
    atomicAdd(counts + slot, 1);
  } else if (bx < 1024) {               // ---- prev transpose [b][16][N] -> [b][n][16] ----
    __shared__ float tile[16][65];
    int bb = bx - 512;
    int b = bb >> 8, n0 = (bb & 255) * 64;
    for (int e = tid; e < 1024; e += 256) {
      int ln = e & 63, r = e >> 6;
      tile[r][ln] = prev[((size_t)b * PREVC + r) * NPTS + n0 + ln];
    }
    __syncthreads();
    for (int e = tid; e < 1024; e += 256) {
      int c = e & 15, nn = e >> 4;
      prevT[((size_t)b * NPTS + n0 + nn) * 16 + c] = tile[c][nn];
    }
  } else if (bx < 1243) {               // ---- weight prep ----
    int e = (bx - 1024) * 256 + tid;
    if (e < CORR * CIN * 32) {
      int o = e & 31, i = (e >> 5) % CIN, k = e / (CIN * 32);
      cwT[e] = cw0[((size_t)o * CIN + i) * CORR + k];
    }
    int e2 = e - CORR * CIN * 32;
    if (e2 >= 0 && e2 < 512 * 64) {
      int o3 = e2 & 63, cf = e2 >> 6, c = cf >> 4, f = cf & 15;
      W0r[e2] = (f < FILT) ? bw0[((size_t)o3 * CO0 + c) * FILT + f] : 0.f;
    }
  } else {                              // ---- pc1/pc2 transpose -> gT (ushort, +1) ----
    __shared__ int tile[16][65];
    int t = bx - 1243;
    int n0 = (t & 63) * 64;
    int rest = t >> 6;                  // 0..31
    int b = rest & 1;
    int rt = rest >> 1;                 // 0..15
    const int* src; int r0, nr, doff;
    if (rt < 15) { src = pc2 + (size_t)b * FILT * CORR * M1; r0 = rt * 16;
                   nr = min(16, FILT * CORR - r0); doff = 0; }
    else         { src = pc1 + (size_t)b * CORR * M1; r0 = 0; nr = CORR; doff = 225; }
    for (int e = tid; e < nr * 64; e += 256) {
      int ln = e & 63, r = e >> 6;
      tile[r][ln] = src[(size_t)(r0 + r) * M1 + n0 + ln] + 1;
    }
    __syncthreads();
    for (int e = tid; e < 1024; e += 256) {
      int rr = e & 15, nn = e >> 4;
      if (rr < nr)
        gT[((size_t)b * M1 + n0 + nn) * GSTR + doff + r0 + rr] =
            (unsigned short)tile[rr][nn];
    }
  }
}

// ============ parallel exclusive scan (one 1024-thread block) ============
__global__ __launch_bounds__(1024) void k_scan(const int* __restrict__ counts,
                                               int* __restrict__ offsets,
                                               int* __restrict__ cursors) {
  __shared__ int wsum[16];
  int t = threadIdx.x;
  int base = t * 9;
  int v[9];
  int s = 0;
#pragma unroll
  for (int i = 0; i < 9; ++i) { v[i] = counts[base + i]; s += v[i]; }
  int lane = t & 63, w = t >> 6;
  int ps = s;
#pragma unroll
  for (int d = 1; d < 64; d <<= 1) {
    int u = __shfl_up(ps, d);
    if (lane >= d) ps += u;
  }
  if (lane == 63) wsum[w] = ps;
  __syncthreads();
  if (w == 0 && lane < 16) {
    int x = wsum[lane];
#pragma unroll
    for (int d = 1; d < 16; d <<= 1) {
      int u = __shfl_up(x, d);
      if (lane >= d) x += u;
    }
    wsum[lane] = x;  // inclusive wave sums
  }
  __syncthreads();
  int excl = ps - s + (w > 0 ? wsum[w - 1] : 0);
#pragma unroll
  for (int i = 0; i < 9; ++i) {
    int idx = base + i;
    offsets[idx] = excl;
    cursors[idx] = excl;
    excl += v[i];
  }
}

// ============ scatter pair ids into slot-sorted order ============
__global__ void k_scatter(const int* __restrict__ lo, int* __restrict__ cursors,
                          int* __restrict__ rec) {
  int t = blockIdx.x * 256 + threadIdx.x;
  int slot = lo[t] + 1;
  int pos = atomicAdd(cursors + slot, 1);
  rec[pos] = t;
}

// ============ per-slot summation + normalize + feat fills ============
__global__ __launch_bounds__(256) void k_sum(const int* __restrict__ rec,
                                             const int* __restrict__ offsets,
                                             const float* __restrict__ bary,
                                             const float* __restrict__ prevT,
                                             const float* __restrict__ feat1,
                                             const float* __restrict__ feat2,
                                             float* __restrict__ splat1,
                                             float* __restrict__ splat2) {
  int tid = threadIdx.x;
  int s = blockIdx.x * 4 + (tid >> 6);
  if (s >= NSLOT) return;
  int lane = tid & 63, c = lane & 15, g = lane >> 4;
  int start = offsets[s], end = offsets[s + 1];
  float acc = 0.f, wsum = 0.f;
  for (int e = start + g; e < end; e += 4) {
    int t = rec[e];
    float w = bary[t];
    int n = t % NPTS;
    int b = t / (D1 * NPTS);
    acc += w * prevT[((size_t)b * NPTS + n) * 16 + c];
    wsum += w;
  }
  acc  += __shfl_down(acc, 32);  acc  += __shfl_down(acc, 16);
  wsum += __shfl_down(wsum, 32); wsum += __shfl_down(wsum, 16);
  if (lane < 16) {
    int m = s % MS, b2 = s / MS;
    float scale = 1.f / (wsum + 1e-5f);
    splat1[(size_t)s * 32 + c] = acc * scale;
    float f1 = (m == 0) ? 0.f : feat1[((size_t)b2 * C + c) * M1 + (m - 1)];
    splat1[(size_t)s * 32 + 16 + c] = f1;
    float f2 = (m == 0) ? 0.f : feat2[((size_t)b2 * C + c) * M1 + (m - 1)];
    splat2[(size_t)s * 16 + c] = f2;
  }
}

// ============ per-slot projections P, Q (bf16 out) ============
__global__ __launch_bounds__(256) void k_pq(const float* __restrict__ sp1,
                                            const float* __restrict__ sp2,
                                            const float* __restrict__ cwT,
                                            __hip_bfloat16* __restrict__ Pt,
                                            __hip_bfloat16* __restrict__ Qt) {
  __shared__ float wk[CIN][33];
  int k = blockIdx.y, b = blockIdx.z;
  int tid = threadIdx.x;
  int m = blockIdx.x * 16 + (tid >> 4);
  int o2 = tid & 15;
  for (int e = tid; e < CIN * 32; e += 256)
    wk[e >> 5][e & 31] = cwT[(size_t)k * CIN * 32 + e];
  __syncthreads();
  if (m >= MS) return;
  const float* s1 = sp1 + ((size_t)b * MS + m) * 32;
  const float* s2 = sp2 + ((size_t)b * MS + m) * 16;
  int oa = o2 * 2, ob = oa + 1;
  float q0 = 0, q1 = 0, p0 = 0, p1 = 0;
#pragma unroll
  for (int i4 = 0; i4 < 8; ++i4) {
    float4 s = *(const float4*)(s1 + i4 * 4);
    q0 += s.x * wk[i4*4+0][oa] + s.y * wk[i4*4+1][oa] + s.z * wk[i4*4+2][oa] + s.w * wk[i4*4+3][oa];
    q1 += s.x * wk[i4*4+0][ob] + s.y * wk[i4*4+1][ob] + s.z * wk[i4*4+2][ob] + s.w * wk[i4*4+3][ob];
  }
#pragma unroll
  for (int i4 = 0; i4 < 4; ++i4) {
    float4 s = *(const float4*)(s2 + i4 * 4);
    p0 += s.x * wk[32+i4*4+0][oa] + s.y * wk[32+i4*4+1][oa] + s.z * wk[32+i4*4+2][oa] + s.w * wk[32+i4*4+3][oa];
    p1 += s.x * wk[32+i4*4+0][ob] + s.y * wk[32+i4*4+1][ob] + s.z * wk[32+i4*4+2][ob] + s.w * wk[32+i4*4+3][ob];
  }
  size_t base = ((size_t)(b * CORR + k) * MS + m) * 32;
  __hip_bfloat162 qq, pp;
  qq.x = __float2bfloat16(q0); qq.y = __float2bfloat16(q1);
  pp.x = __float2bfloat16(p0); pp.y = __float2bfloat16(p1);
  *reinterpret_cast<__hip_bfloat162*>(Qt + base + oa) = qq;
  *reinterpret_cast<__hip_bfloat162*>(Pt + base + oa) = pp;
}

// ============ gather + corr-conv; stage1: 256 thr = o2(16) x f(16), dword gathers ============
// XCD batch swizzle: XCDs 0-3 process b=0, XCDs 4-7 b=1 (assumes bid%8 round-robin)
__global__ __launch_bounds__(256) void k_gather(const __hip_bfloat16* __restrict__ Pt,
                                                const __hip_bfloat16* __restrict__ Qt,
                                                const unsigned short* __restrict__ gT,
                                                const float* __restrict__ cw1,
                                                const float* __restrict__ cb0,
                                                const float* __restrict__ cb1,
                                                __hip_bfloat16* __restrict__ hbuf) {
  __shared__ unsigned short idxs[GSTR];
  __shared__ float p1s[32];            // part1 + cb0, per o
  __shared__ float cw1T[32][33];
  __shared__ float xls[16][36];        // xls[f][o], rows 0..14 valid
  __shared__ float hT[32 * 17];

  int bid = blockIdx.x;
  int b = (bid >> 2) & 1;
  int n = ((bid & 3) << 10) | (bid >> 3);
  int pt = (b << 12) | n;              // b*M1 + n
  int tid = threadIdx.x;

  if (tid < GSTR / 2)                  // stage indices as dwords
    ((unsigned int*)idxs)[tid] =
        ((const unsigned int*)(gT + (size_t)pt * GSTR))[tid];
  {
    int oo = tid >> 3, c0 = (tid & 7) * 4;
    float4 wv = *(const float4*)(cw1 + oo * CO0 + c0);
    cw1T[c0+0][oo] = wv.x; cw1T[c0+1][oo] = wv.y;
    cw1T[c0+2][oo] = wv.z; cw1T[c0+3][oo] = wv.w;
  }
  __syncthreads();

  // ---- stage 1: gather-sum. thread (o2, f): o-pair {2o2, 2o2+1} of conv-row f.
  // f in 0..14: P rows via idx2[f][k];  f == 15: Q rows via idx1[k] (part1).
  {
    int o2 = tid & 15, f = tid >> 4;
    const __hip_bfloat16* base =
        (f < CORR ? Pt : Qt) + (size_t)b * CORR * MS * 32;
    const unsigned short* ip = &idxs[f < CORR ? f * CORR : 225];
    float a0 = 0.f, a1 = 0.f;
#pragma unroll
    for (int k = 0; k < CORR; ++k) {
      unsigned int idx = ip[k];
      unsigned int d = *(const unsigned int*)(base + ((size_t)k * MS + idx) * 32 + o2 * 2);
      a0 += __uint_as_float(d << 16);
      a1 += __uint_as_float(d & 0xffff0000u);
    }
    if (f == CORR) {                   // part1 + bias
      p1s[o2 * 2]     = a0 + cb0[o2 * 2];
      p1s[o2 * 2 + 1] = a1 + cb0[o2 * 2 + 1];
    }
    __syncthreads();
    if (f < CORR) {
      xls[f][o2 * 2]     = leaky(a0 + p1s[o2 * 2]);
      xls[f][o2 * 2 + 1] = leaky(a1 + p1s[o2 * 2 + 1]);
    }
  }
  __syncthreads();

  // ---- stage 2: 1x1 conv over c=32, two f's per thread ----
  {
    int o = tid & 31, fg = tid >> 5;
    float h0 = cb1[o], h1 = h0;
#pragma unroll
    for (int c = 0; c < 32; ++c) {
      float w = cw1T[c][o];
      h0 += w * xls[fg][c];
      if (fg < 7) h1 += w * xls[fg + 8][c];
    }
    hT[o * 17 + fg] = leaky(h0);
    if (fg < 7) hT[o * 17 + fg + 8] = leaky(h1);
    else        hT[o * 17 + 15] = 0.f;
  }
  __syncthreads();

  int cf0 = tid * 2;
  int oo = cf0 >> 4, ff = cf0 & 15;
  __hip_bfloat162 hv;
  hv.x = __float2bfloat16(hT[oo * 17 + ff]);
  hv.y = __float2bfloat16(hT[oo * 17 + ff + 1]);
  *reinterpret_cast<__hip_bfloat162*>(hbuf + (size_t)pt * 512 + cf0) = hv;
}

// ============ blur conv ============
__global__ __launch_bounds__(256) void k_blur(const __hip_bfloat16* __restrict__ hbuf,
                                              const float* __restrict__ W0r,
                                              const float* __restrict__ bb0,
                                              const float* __restrict__ bw1,
                                              const float* __restrict__ bb1,
                                              float* __restrict__ out) {
  __shared__ float hs[64][33];
  __shared__ float ws[64][68];
  __shared__ float y0s[64][36];

  int bid = blockIdx.x;
  int b = bid >> 7;
  int n0 = (bid & 127) * 32;
  int tid = threadIdx.x;
  int og = tid & 15, ng = tid >> 4;

  float acc[4][2] = {};
  for (int kc = 0; kc < 512; kc += 64) {
    __syncthreads();
    {   // stage h chunk (bf16 -> f32), transposed: hs[kk][nn]
      int nn = tid >> 3, k8 = tid & 7;
      const __hip_bfloat16* hp = hbuf + ((size_t)b * M1 + n0 + nn) * 512 + kc + k8 * 8;
#pragma unroll
      for (int j = 0; j < 4; ++j) {
        __hip_bfloat162 v2 = *(const __hip_bfloat162*)(hp + j * 2);
        hs[k8 * 8 + j * 2 + 0][nn] = __bfloat162float(v2.x);
        hs[k8 * 8 + j * 2 + 1][nn] = __bfloat162float(v2.y);
      }
    }
    for (int e = tid; e < 1024; e += 256) {
      int row = e >> 4, c4 = e & 15;
      *(float4*)&ws[row][c4 * 4] = *(const float4*)(W0r + (size_t)(kc + row) * 64 + c4 * 4);
    }
    __syncthreads();
#pragma unroll 16
    for (int kk = 0; kk < 64; ++kk) {
      float4 w = *(const float4*)&ws[kk][og * 4];
      float h0 = hs[kk][ng * 2], h1 = hs[kk][ng * 2 + 1];
      acc[0][0] += w.x * h0; acc[0][1] += w.x * h1;
      acc[1][0] += w.y * h0; acc[1][1] += w.y * h1;
      acc[2][0] += w.z * h0; acc[2][1] += w.z * h1;
      acc[3][0] += w.w * h0; acc[3][1] += w.w * h1;
    }
  }
  __syncthreads();

#pragma unroll
  for (int i = 0; i < 4; ++i) {
    int o3 = og * 4 + i;
    float bias = bb0[o3];
#pragma unroll
    for (int j = 0; j < 2; ++j)
      y0s[o3][ng * 2 + j] = leaky(acc[i][j] + bias);
  }
  for (int e = tid; e < 64 * 64; e += 256) {
    int o1e = e >> 6, c = e & 63;
    ws[c][o1e] = bw1[e];
  }
  __syncthreads();

  int o1 = tid & 63, ng4 = tid >> 6;
  float a8[8] = {};
  for (int c = 0; c < 64; ++c) {
    float w = ws[c][o1];
    float4 ya = *(const float4*)&y0s[c][ng4 * 8];
    float4 yb = *(const float4*)&y0s[c][ng4 * 8 + 4];
    a8[0] += w * ya.x; a8[1] += w * ya.y; a8[2] += w * ya.z; a8[3] += w * ya.w;
    a8[4] += w * yb.x; a8[5] += w * yb.y; a8[6] += w * yb.z; a8[7] += w * yb.w;
  }
  float bias = bb1[o1];
#pragma unroll
  for (int j = 0; j < 8; ++j)
    out[((size_t)b * O1 + o1) * M1 + n0 + ng4 * 8 + j] = a8[j] + bias;
}

}  // namespace

extern "C" void kernel_launch(void* const* d_in, const int* in_sizes, int n_in,
                              void* d_out, int out_size, void* d_ws, size_t ws_size,
                              hipStream_t stream) {
  const float* feat1 = (const float*)d_in[0];
  const float* feat2 = (const float*)d_in[1];
  const float* prev  = (const float*)d_in[2];
  const float* bary  = (const float*)d_in[3];
  const float* cw0   = (const float*)d_in[4];
  const float* cb0   = (const float*)d_in[5];
  const float* cw1   = (const float*)d_in[6];
  const float* cb1   = (const float*)d_in[7];
  const float* bw0   = (const float*)d_in[8];
  const float* bb0   = (const float*)d_in[9];
  const float* bw1   = (const float*)d_in[10];
  const float* bb1   = (const float*)d_in[11];
  const int* lo  = (const int*)d_in[12];
  const int* pc1 = (const int*)d_in[13];
  const int* pc2 = (const int*)d_in[14];

  float* ws = (float*)d_ws;
  float* splat1 = ws + OFF_SP1;
  float* splat2 = ws + OFF_SP2;
  __hip_bfloat16* Pt = (__hip_bfloat16*)(ws + OFF_P);
  __hip_bfloat16* Qt = (__hip_bfloat16*)(ws + OFF_Q);
  float* cwT   = ws + OFF_CWT;
  float* W0r   = ws + OFF_W0R;
  __hip_bfloat16* hbuf = (__hip_bfloat16*)(ws + OFF_H);
  float* prevT = ws + OFF_PREVT;
  int* counts  = (int*)(ws + OFF_CNT);
  int* offsets = (int*)(ws + OFF_OFFS);
  int* cursors = (int*)(ws + OFF_CURS);
  int* rec     = (int*)(ws + OFF_REC);
  unsigned short* gT = (unsigned short*)(ws + OFF_GT);
  float* out   = (float*)d_out;

  hipMemsetAsync(counts, 0, NSCAN * sizeof(int), stream);

  hipLaunchKernelGGL(k_pre, dim3(1243 + 2048), dim3(256), 0, stream,
                     lo, prev, cw0, bw0, pc1, pc2, counts, prevT, cwT, W0r, gT);
  hipLaunchKernelGGL(k_scan, dim3(1), dim3(1024), 0, stream, counts, offsets, cursors);
  hipLaunchKernelGGL(k_scatter, dim3(NPAIR / 256), dim3(256), 0, stream, lo, cursors, rec);
  hipLaunchKernelGGL(k_sum, dim3((NSLOT + 3) / 4), dim3(256), 0, stream,
                     rec, offsets, bary, prevT, feat1, feat2, splat1, splat2);
  hipLaunchKernelGGL(k_pq, dim3((MS + 15) / 16, CORR, B), dim3(256), 0, stream,
                     splat1, splat2, cwT, Pt, Qt);
  hipLaunchKernelGGL(k_gather, dim3(B * M1), dim3(256), 0, stream,
                     Pt, Qt, gT, cw1, cb0, cb1, hbuf);
  hipLaunchKernelGGL(k_blur, dim3(B * M1 / 32), dim3(256), 0, stream,
                     hbuf, W0r, bb0, bw1, bb1, out);
}

// Round 6
// 124.817 us; speedup vs baseline: 3.9749x; 1.0320x over previous
//
#include <hip/hip_runtime.h>
#include <hip/hip_bf16.h>

namespace {

constexpr int B     = 2;
constexpr int C     = 16;
constexpr int PREVC = 16;
constexpr int NPTS  = 16384;
constexpr int M1    = 4096;
constexpr int D1    = 4;
constexpr int CORR  = 15;
constexpr int FILT  = 15;
constexpr int CIN   = 48;
constexpr int CO0   = 32;
constexpr int O1    = 64;
constexpr int MS    = M1 + 1;        // 4097
constexpr int NSLOT = B * MS;        // 8194
constexpr int NPAIR = B * D1 * NPTS; // 131072
constexpr int BCAP  = 64;            // bucket capacity (mean 16, P(>64) ~ 0)
constexpr int GSTR  = 240;           // 225 idx2 + 15 idx1 (ushort, +1 folded)
constexpr float NEG = 0.1f;

// ---- workspace layout (float units) ----
constexpr size_t OFF_SP1   = 0;                               // splat1 [slot][32] f32
constexpr size_t SZ_SP1    = (size_t)NSLOT * 32;
constexpr size_t OFF_SP2   = OFF_SP1 + SZ_SP1;                // splat2 [slot][16] f32
constexpr size_t SZ_SP2    = (size_t)NSLOT * 16;
constexpr size_t OFF_P     = OFF_SP2 + SZ_SP2;                // P bf16 [b][k][m][32]
constexpr size_t SZ_PQ     = (size_t)B * CORR * MS * 32 / 2;
constexpr size_t OFF_Q     = OFF_P + SZ_PQ;                   // Q bf16
constexpr size_t OFF_CWT   = OFF_Q + SZ_PQ;                   // cwT [k][i48][o32] f32
constexpr size_t SZ_CWT    = (size_t)CORR * CIN * 32;
constexpr size_t OFF_W0R   = OFF_CWT + SZ_CWT;                // W0r [cf512][o64] f32
constexpr size_t SZ_W0R    = 512 * 64;
constexpr size_t OFF_H     = OFF_W0R + SZ_W0R;                // h bf16 [b][n][512]
constexpr size_t SZ_H      = (size_t)B * M1 * 512 / 2;
constexpr size_t OFF_PREVT = OFF_H + SZ_H;                    // prevT [b][n][16] f32
constexpr size_t SZ_PREVT  = (size_t)B * NPTS * 16;
constexpr size_t OFF_CNT   = OFF_PREVT + SZ_PREVT;            // counts (int)
constexpr size_t SZ_CNT    = 8208;                            // >= NSLOT, padded
constexpr size_t OFF_REC   = OFF_CNT + SZ_CNT;                // rec (int) [slot][64]
constexpr size_t SZ_REC    = (size_t)NSLOT * BCAP;
constexpr size_t OFF_GT    = OFF_REC + SZ_REC;                // gT (ushort) [b*M1][240]
constexpr size_t SZ_GT     = (size_t)B * M1 * GSTR / 2;
// end ~8.52M floats ~= 34 MB

__device__ __forceinline__ float leaky(float v) { return v > 0.f ? v : NEG * v; }
__device__ __forceinline__ float bflo(unsigned u) { return __uint_as_float(u << 16); }
__device__ __forceinline__ float bfhi(unsigned u) { return __uint_as_float(u & 0xffff0000u); }

// ===== fused prep: count+bucket-scatter | prev transpose | weight prep | pc transpose =====
__global__ __launch_bounds__(256) void k_pre(const int* __restrict__ lo,
                                             const float* __restrict__ prev,
                                             const float* __restrict__ cw0,
                                             const float* __restrict__ bw0,
                                             const int* __restrict__ pc1,
                                             const int* __restrict__ pc2,
                                             int* __restrict__ counts,
                                             int* __restrict__ rec,
                                             float* __restrict__ prevT,
                                             float* __restrict__ cwT,
                                             float* __restrict__ W0r,
                                             unsigned short* __restrict__ gT) {
  int bx = blockIdx.x, tid = threadIdx.x;
  if (bx < 512) {                       // ---- count + direct bucket scatter ----
    int t = bx * 256 + tid;
    int slot = lo[t] + 1;
    int pos = atomicAdd(counts + slot, 1);
    if (pos < BCAP) rec[slot * BCAP + pos] = t;
  } else if (bx < 1024) {               // ---- prev transpose [b][16][N] -> [b][n][16] ----
    __shared__ float tile[16][65];
    int bb = bx - 512;
    int b = bb >> 8, n0 = (bb & 255) * 64;
    for (int e = tid; e < 1024; e += 256) {
      int ln = e & 63, r = e >> 6;
      tile[r][ln] = prev[((size_t)b * PREVC + r) * NPTS + n0 + ln];
    }
    __syncthreads();
    for (int e = tid; e < 1024; e += 256) {
      int c = e & 15, nn = e >> 4;
      prevT[((size_t)b * NPTS + n0 + nn) * 16 + c] = tile[c][nn];
    }
  } else if (bx < 1243) {               // ---- weight prep ----
    int e = (bx - 1024) * 256 + tid;
    if (e < CORR * CIN * 32) {
      int o = e & 31, i = (e >> 5) % CIN, k = e / (CIN * 32);
      cwT[e] = cw0[((size_t)o * CIN + i) * CORR + k];
    }
    int e2 = e - CORR * CIN * 32;
    if (e2 >= 0 && e2 < 512 * 64) {
      int o3 = e2 & 63, cf = e2 >> 6, c = cf >> 4, f = cf & 15;
      W0r[e2] = (f < FILT) ? bw0[((size_t)o3 * CO0 + c) * FILT + f] : 0.f;
    }
  } else {                              // ---- pc1/pc2 transpose -> gT (ushort, +1) ----
    __shared__ int tile[16][65];
    int t = bx - 1243;
    int n0 = (t & 63) * 64;
    int rest = t >> 6;                  // 0..31
    int b = rest & 1;
    int rt = rest >> 1;                 // 0..15
    const int* src; int r0, nr, doff;
    if (rt < 15) { src = pc2 + (size_t)b * FILT * CORR * M1; r0 = rt * 16;
                   nr = min(16, FILT * CORR - r0); doff = 0; }
    else         { src = pc1 + (size_t)b * CORR * M1; r0 = 0; nr = CORR; doff = 225; }
    for (int e = tid; e < nr * 64; e += 256) {
      int ln = e & 63, r = e >> 6;
      tile[r][ln] = src[(size_t)(r0 + r) * M1 + n0 + ln] + 1;
    }
    __syncthreads();
    for (int e = tid; e < 1024; e += 256) {
      int rr = e & 15, nn = e >> 4;
      if (rr < nr)
        gT[((size_t)b * M1 + n0 + nn) * GSTR + doff + r0 + rr] =
            (unsigned short)tile[rr][nn];
    }
  }
}

// ===== per-slot bucket summation + normalize + feat fills =====
__global__ __launch_bounds__(256) void k_sum(const int* __restrict__ rec,
                                             const int* __restrict__ counts,
                                             const float* __restrict__ bary,
                                             const float* __restrict__ prevT,
                                             const float* __restrict__ feat1,
                                             const float* __restrict__ feat2,
                                             float* __restrict__ splat1,
                                             float* __restrict__ splat2) {
  int tid = threadIdx.x;
  int s = blockIdx.x * 4 + (tid >> 6);
  if (s >= NSLOT) return;
  int lane = tid & 63, c = lane & 15, g = lane >> 4;
  int cnt = min(counts[s], BCAP);
  const int* bucket = rec + (size_t)s * BCAP;
  float acc = 0.f, wsum = 0.f;
  for (int e = g; e < cnt; e += 4) {
    int t = bucket[e];
    float w = bary[t];
    int n = t & (NPTS - 1);
    int b = t >> 16;                    // D1*NPTS = 65536
    acc += w * prevT[((size_t)b * NPTS + n) * 16 + c];
    wsum += w;
  }
  acc  += __shfl_down(acc, 32);  acc  += __shfl_down(acc, 16);
  wsum += __shfl_down(wsum, 32); wsum += __shfl_down(wsum, 16);
  if (lane < 16) {
    int m = s % MS, b2 = s / MS;
    float scale = 1.f / (wsum + 1e-5f);
    splat1[(size_t)s * 32 + c] = acc * scale;
    float f1 = (m == 0) ? 0.f : feat1[((size_t)b2 * C + c) * M1 + (m - 1)];
    splat1[(size_t)s * 32 + 16 + c] = f1;
    float f2 = (m == 0) ? 0.f : feat2[((size_t)b2 * C + c) * M1 + (m - 1)];
    splat2[(size_t)s * 16 + c] = f2;
  }
}

// ===== per-slot projections P, Q (bf16 out) =====
__global__ __launch_bounds__(256) void k_pq(const float* __restrict__ sp1,
                                            const float* __restrict__ sp2,
                                            const float* __restrict__ cwT,
                                            __hip_bfloat16* __restrict__ Pt,
                                            __hip_bfloat16* __restrict__ Qt) {
  __shared__ float wk[CIN][33];
  int k = blockIdx.y, b = blockIdx.z;
  int tid = threadIdx.x;
  int m = blockIdx.x * 16 + (tid >> 4);
  int o2 = tid & 15;
  for (int e = tid; e < CIN * 32; e += 256)
    wk[e >> 5][e & 31] = cwT[(size_t)k * CIN * 32 + e];
  __syncthreads();
  if (m >= MS) return;
  const float* s1 = sp1 + ((size_t)b * MS + m) * 32;
  const float* s2 = sp2 + ((size_t)b * MS + m) * 16;
  int oa = o2 * 2, ob = oa + 1;
  float q0 = 0, q1 = 0, p0 = 0, p1 = 0;
#pragma unroll
  for (int i4 = 0; i4 < 8; ++i4) {
    float4 s = *(const float4*)(s1 + i4 * 4);
    q0 += s.x * wk[i4*4+0][oa] + s.y * wk[i4*4+1][oa] + s.z * wk[i4*4+2][oa] + s.w * wk[i4*4+3][oa];
    q1 += s.x * wk[i4*4+0][ob] + s.y * wk[i4*4+1][ob] + s.z * wk[i4*4+2][ob] + s.w * wk[i4*4+3][ob];
  }
#pragma unroll
  for (int i4 = 0; i4 < 4; ++i4) {
    float4 s = *(const float4*)(s2 + i4 * 4);
    p0 += s.x * wk[32+i4*4+0][oa] + s.y * wk[32+i4*4+1][oa] + s.z * wk[32+i4*4+2][oa] + s.w * wk[32+i4*4+3][oa];
    p1 += s.x * wk[32+i4*4+0][ob] + s.y * wk[32+i4*4+1][ob] + s.z * wk[32+i4*4+2][ob] + s.w * wk[32+i4*4+3][ob];
  }
  size_t base = ((size_t)(b * CORR + k) * MS + m) * 32;
  __hip_bfloat162 qq, pp;
  qq.x = __float2bfloat16(q0); qq.y = __float2bfloat16(q1);
  pp.x = __float2bfloat16(p0); pp.y = __float2bfloat16(p1);
  *reinterpret_cast<__hip_bfloat162*>(Qt + base + oa) = qq;
  *reinterpret_cast<__hip_bfloat162*>(Pt + base + oa) = pp;
}

// ===== gather + corr-conv; 4 points/block, 16B gather loads, reg->global h store =====
// wave = one point: lanes (f 0..15) x (o4 0..3); XCD batch swizzle via bid%8
__global__ __launch_bounds__(256) void k_gather(const __hip_bfloat16* __restrict__ Pt,
                                                const __hip_bfloat16* __restrict__ Qt,
                                                const unsigned short* __restrict__ gT,
                                                const float* __restrict__ cw1,
                                                const float* __restrict__ cb0,
                                                const float* __restrict__ cb1,
                                                __hip_bfloat16* __restrict__ hbuf) {
  __shared__ unsigned short idxs[4][GSTR];
  __shared__ float p1s[4][32];
  __shared__ float xls[4][16][33];     // [pl][f][o], row 15 unused

  int bid = blockIdx.x;                // 2048 blocks
  int b = (bid >> 2) & 1;              // bid%8 in {0..3} -> b=0 (XCD 0-3), {4..7} -> b=1
  int r = bid & 3, x = bid >> 3;       // x in 0..255
  int n0 = (r << 10) | (x << 2);
  int pt0 = (b << 12) | n0;
  int tid = threadIdx.x;

  for (int e = tid; e < 480; e += 256) {     // 4 pts x 120 dwords of indices
    int pl = e / 120, d = e - pl * 120;
    ((unsigned int*)idxs[pl])[d] =
        ((const unsigned int*)(gT + (size_t)(pt0 + pl) * GSTR))[d];
  }
  __syncthreads();

  int pl = tid >> 6, lane = tid & 63;
  int f = lane >> 2, o4 = lane & 3;    // 4 lanes per row -> one 64B line per (f,k)

  // ---- stage 1: gather-sum 8 o's per thread ----
  {
    const __hip_bfloat16* base = (f < CORR ? Pt : Qt) + (size_t)b * CORR * MS * 32;
    const unsigned short* ip = &idxs[pl][f < CORR ? f * CORR : 225];
    float a[8] = {};
#pragma unroll
    for (int k = 0; k < CORR; ++k) {
      unsigned int idx = ip[k];
      uint4 d = *(const uint4*)(base + ((size_t)k * MS + idx) * 32 + o4 * 8);
      a[0] += bflo(d.x); a[1] += bfhi(d.x);
      a[2] += bflo(d.y); a[3] += bfhi(d.y);
      a[4] += bflo(d.z); a[5] += bfhi(d.z);
      a[6] += bflo(d.w); a[7] += bfhi(d.w);
    }
    if (f == CORR) {
#pragma unroll
      for (int j = 0; j < 8; ++j)
        p1s[pl][o4 * 8 + j] = a[j] + cb0[o4 * 8 + j];
    }
    __syncthreads();
    if (f < CORR) {
#pragma unroll
      for (int j = 0; j < 8; ++j)
        xls[pl][f][o4 * 8 + j] = leaky(a[j] + p1s[pl][o4 * 8 + j]);
    }
  }
  __syncthreads();

  // ---- stage 2: 1x1 conv, 8 f's per thread, direct bf16 store ----
  {
    int o = lane & 31, fh = lane >> 5;
    const float* wrow = cw1 + o * CO0;           // L1-resident (4 KB)
    float bias = cb1[o];
    float h[8];
#pragma unroll
    for (int j = 0; j < 8; ++j) {
      float hh = bias;
#pragma unroll
      for (int c4 = 0; c4 < 8; ++c4) {
        float4 xv = *(const float4*)&xls[pl][fh * 8 + j][c4 * 4];
        float4 w  = *(const float4*)(wrow + c4 * 4);
        hh += w.x * xv.x + w.y * xv.y + w.z * xv.z + w.w * xv.w;
      }
      h[j] = leaky(hh);
    }
    if (fh == 1) h[7] = 0.f;                     // cf slot f==15 pad
    union { __hip_bfloat16 hb[8]; uint4 u; } pk;
#pragma unroll
    for (int j = 0; j < 8; ++j) pk.hb[j] = __float2bfloat16(h[j]);
    *(uint4*)(hbuf + (size_t)(pt0 + pl) * 512 + o * 16 + fh * 8) = pk.u;
  }
}

// ===== blur conv =====
__global__ __launch_bounds__(256) void k_blur(const __hip_bfloat16* __restrict__ hbuf,
                                              const float* __restrict__ W0r,
                                              const float* __restrict__ bb0,
                                              const float* __restrict__ bw1,
                                              const float* __restrict__ bb1,
                                              float* __restrict__ out) {
  __shared__ float hs[64][33];
  __shared__ float ws[64][68];
  __shared__ float y0s[64][36];

  int bid = blockIdx.x;
  int b = bid >> 7;
  int n0 = (bid & 127) * 32;
  int tid = threadIdx.x;
  int og = tid & 15, ng = tid >> 4;

  float acc[4][2] = {};
  for (int kc = 0; kc < 512; kc += 64) {
    __syncthreads();
    {
      int nn = tid >> 3, k8 = tid & 7;
      const __hip_bfloat16* hp = hbuf + ((size_t)b * M1 + n0 + nn) * 512 + kc + k8 * 8;
#pragma unroll
      for (int j = 0; j < 4; ++j) {
        __hip_bfloat162 v2 = *(const __hip_bfloat162*)(hp + j * 2);
        hs[k8 * 8 + j * 2 + 0][nn] = __bfloat162float(v2.x);
        hs[k8 * 8 + j * 2 + 1][nn] = __bfloat162float(v2.y);
      }
    }
    for (int e = tid; e < 1024; e += 256) {
      int row = e >> 4, c4 = e & 15;
      *(float4*)&ws[row][c4 * 4] = *(const float4*)(W0r + (size_t)(kc + row) * 64 + c4 * 4);
    }
    __syncthreads();
#pragma unroll 16
    for (int kk = 0; kk < 64; ++kk) {
      float4 w = *(const float4*)&ws[kk][og * 4];
      float h0 = hs[kk][ng * 2], h1 = hs[kk][ng * 2 + 1];
      acc[0][0] += w.x * h0; acc[0][1] += w.x * h1;
      acc[1][0] += w.y * h0; acc[1][1] += w.y * h1;
      acc[2][0] += w.z * h0; acc[2][1] += w.z * h1;
      acc[3][0] += w.w * h0; acc[3][1] += w.w * h1;
    }
  }
  __syncthreads();

#pragma unroll
  for (int i = 0; i < 4; ++i) {
    int o3 = og * 4 + i;
    float bias = bb0[o3];
#pragma unroll
    for (int j = 0; j < 2; ++j)
      y0s[o3][ng * 2 + j] = leaky(acc[i][j] + bias);
  }
  for (int e = tid; e < 64 * 64; e += 256) {
    int o1e = e >> 6, c = e & 63;
    ws[c][o1e] = bw1[e];
  }
  __syncthreads();

  int o1 = tid & 63, ng4 = tid >> 6;
  float a8[8] = {};
  for (int c = 0; c < 64; ++c) {
    float w = ws[c][o1];
    float4 ya = *(const float4*)&y0s[c][ng4 * 8];
    float4 yb = *(const float4*)&y0s[c][ng4 * 8 + 4];
    a8[0] += w * ya.x; a8[1] += w * ya.y; a8[2] += w * ya.z; a8[3] += w * ya.w;
    a8[4] += w * yb.x; a8[5] += w * yb.y; a8[6] += w * yb.z; a8[7] += w * yb.w;
  }
  float bias = bb1[o1];
#pragma unroll
  for (int j = 0; j < 8; ++j)
    out[((size_t)b * O1 + o1) * M1 + n0 + ng4 * 8 + j] = a8[j] + bias;
}

}  // namespace

extern "C" void kernel_launch(void* const* d_in, const int* in_sizes, int n_in,
                              void* d_out, int out_size, void* d_ws, size_t ws_size,
                              hipStream_t stream) {
  const float* feat1 = (const float*)d_in[0];
  const float* feat2 = (const float*)d_in[1];
  const float* prev  = (const float*)d_in[2];
  const float* bary  = (const float*)d_in[3];
  const float* cw0   = (const float*)d_in[4];
  const float* cb0   = (const float*)d_in[5];
  const float* cw1   = (const float*)d_in[6];
  const float* cb1   = (const float*)d_in[7];
  const float* bw0   = (const float*)d_in[8];
  const float* bb0   = (const float*)d_in[9];
  const float* bw1   = (const float*)d_in[10];
  const float* bb1   = (const float*)d_in[11];
  const int* lo  = (const int*)d_in[12];
  const int* pc1 = (const int*)d_in[13];
  const int* pc2 = (const int*)d_in[14];

  float* ws = (float*)d_ws;
  float* splat1 = ws + OFF_SP1;
  float* splat2 = ws + OFF_SP2;
  __hip_bfloat16* Pt = (__hip_bfloat16*)(ws + OFF_P);
  __hip_bfloat16* Qt = (__hip_bfloat16*)(ws + OFF_Q);
  float* cwT   = ws + OFF_CWT;
  float* W0r   = ws + OFF_W0R;
  __hip_bfloat16* hbuf = (__hip_bfloat16*)(ws + OFF_H);
  float* prevT = ws + OFF_PREVT;
  int* counts  = (int*)(ws + OFF_CNT);
  int* rec     = (int*)(ws + OFF_REC);
  unsigned short* gT = (unsigned short*)(ws + OFF_GT);
  float* out   = (float*)d_out;

  hipMemsetAsync(counts, 0, NSLOT * sizeof(int), stream);

  hipLaunchKernelGGL(k_pre, dim3(1243 + 2048), dim3(256), 0, stream,
                     lo, prev, cw0, bw0, pc1, pc2, counts, rec, prevT, cwT, W0r, gT);
  hipLaunchKernelGGL(k_sum, dim3((NSLOT + 3) / 4), dim3(256), 0, stream,
                     rec, counts, bary, prevT, feat1, feat2, splat1, splat2);
  hipLaunchKernelGGL(k_pq, dim3((MS + 15) / 16, CORR, B), dim3(256), 0, stream,
                     splat1, splat2, cwT, Pt, Qt);
  hipLaunchKernelGGL(k_gather, dim3(B * M1 / 4), dim3(256), 0, stream,
                     Pt, Qt, gT, cw1, cb0, cb1, hbuf);
  hipLaunchKernelGGL(k_blur, dim3(B * M1 / 32), dim3(256), 0, stream,
                     hbuf, W0r, bb0, bw1, bb1, out);
}